// Round 1
// baseline (643.054 us; speedup 1.0000x reference)
//
#include <hip/hip_runtime.h>
#include <hip/hip_bf16.h>
#include <math.h>

typedef __bf16 bf16;
typedef bf16 bf16x8 __attribute__((ext_vector_type(8)));
typedef bf16 bf16x2 __attribute__((ext_vector_type(2)));
typedef float f32x4 __attribute__((ext_vector_type(4)));

#define B_   2
#define N_   2048
#define D_   1024
#define H_   16
#define HC_  8
#define M_   (B_*N_)   // 4096 rows in all big GEMMs

// async global->LDS 16B: lds dest = wave-uniform base + lane*16
__device__ __forceinline__ void gl16(const bf16* g, bf16* lds_base) {
#if __has_builtin(__builtin_amdgcn_global_load_lds)
  __builtin_amdgcn_global_load_lds((const __attribute__((address_space(1))) void*)g,
                                   (__attribute__((address_space(3))) void*)lds_base,
                                   16, 0, 0);
#else
  int lane = threadIdx.x & 63;
  *(uint4*)(lds_base + lane * 8) = *(const uint4*)g;
#endif
}

// packed f32 pair -> bf16x2 (RNE), single instruction
__device__ __forceinline__ bf16x2 cvt_pk_bf16(float lo, float hi) {
  unsigned int r;
  asm("v_cvt_pk_bf16_f32 %0, %1, %2" : "=v"(r) : "v"(lo), "v"(hi));
  union { unsigned int u; bf16x2 v; } c;
  c.u = r;
  return c.v;
}

// ============================================================
// Stage A: time-conditioning MLP (GEMV, B=2 rows)
// ============================================================
__global__ __launch_bounds__(256) void emb_kernel(const float* __restrict__ tin,
                                                  float* __restrict__ emb) {
  int idx = blockIdx.x * 256 + threadIdx.x;   // 0..8191
  int b = idx >> 12, p = idx & 4095;
  float tv = tin[b];
  int half = p & 2047;
  float freq = expf(-logf(10000.f) * (float)half * (1.f / 2048.f));
  float arg = tv * freq;
  emb[idx] = (p < 2048) ? cosf(arg) : sinf(arg);
}

// split-K 64-deep (grid (8,64) = 512 blocks -> 2/CU, more loads in flight)
__global__ __launch_bounds__(256) void gemv_kernel(const float* __restrict__ x,
                                                   const float* __restrict__ W,
                                                   float* __restrict__ part) {
  __shared__ float xs[2][64];
  int t = threadIdx.x;
  int j0 = blockIdx.x * 512;
  int k0 = blockIdx.y * 64;
  if (t < 64) xs[0][t] = x[k0 + t];
  else if (t < 128) xs[1][t - 64] = x[4096 + k0 + (t - 64)];
  __syncthreads();
  float a00 = 0.f, a01 = 0.f, a10 = 0.f, a11 = 0.f;
  int j = j0 + t * 2;
  #pragma unroll 8
  for (int k = 0; k < 64; k++) {
    float2 wv = *(const float2*)(W + (size_t)(k0 + k) * 4096 + j);
    float x0 = xs[0][k], x1 = xs[1][k];
    a00 += x0 * wv.x; a01 += x0 * wv.y;
    a10 += x1 * wv.x; a11 += x1 * wv.y;
  }
  *(float2*)(part + (size_t)(blockIdx.y * 2 + 0) * 4096 + j) = make_float2(a00, a01);
  *(float2*)(part + (size_t)(blockIdx.y * 2 + 1) * 4096 + j) = make_float2(a10, a11);
}

__global__ __launch_bounds__(256) void gemv_reduce_kernel(const float* __restrict__ part,
                                                          const float* __restrict__ bias,
                                                          float* __restrict__ y, int act) {
  int idx = blockIdx.x * 256 + threadIdx.x;   // 0..8191
  int b = idx >> 12, j = idx & 4095;
  float s = bias[j];
  #pragma unroll
  for (int kc = 0; kc < 64; kc++) s += part[(size_t)(kc * 2 + b) * 4096 + j];
  if (act) s = s / (1.f + expf(-s));          // silu
  y[idx] = s;
}

__global__ __launch_bounds__(256) void postA_kernel(const float* __restrict__ avec,
                                                    const float* __restrict__ cvec,
                                                    const float* __restrict__ g1,
                                                    const float* __restrict__ g2,
                                                    float* __restrict__ sca, float* __restrict__ scc,
                                                    float* __restrict__ agv, float* __restrict__ cgv) {
  int idx = blockIdx.x * 256 + threadIdx.x;   // 0..2047
  int b = idx >> 10, d = idx & 1023;
  sca[idx] = expf(avec[b * 4096 + 3072 + d]);
  scc[idx] = expf(cvec[b * 4096 + 3072 + d]);
  agv[idx] = avec[b * 4096 + 2048 + d] * g1[d];
  cgv[idx] = cvec[b * 4096 + 2048 + d] * g2[d];
}

// ============================================================
// Weight fp32 (K x N) -> bf16 transposed (N x K), 6 weights in one launch
// ============================================================
__global__ __launch_bounds__(256) void wtconv6_kernel(const float* w0, const float* w1,
                                                      const float* w2, const float* w3,
                                                      const float* w4, const float* w5,
                                                      bf16* o0, bf16* o1, bf16* o2,
                                                      bf16* o3, bf16* o4, bf16* o5) {
  const float* W; bf16* Wt;
  switch (blockIdx.z) {
    case 0: W = w0; Wt = o0; break;
    case 1: W = w1; Wt = o1; break;
    case 2: W = w2; Wt = o2; break;
    case 3: W = w3; Wt = o3; break;
    case 4: W = w4; Wt = o4; break;
    default: W = w5; Wt = o5; break;
  }
  __shared__ float tile[32][33];
  int t = threadIdx.x;
  int i = t >> 5, j = t & 31;
  int n0 = blockIdx.x * 32, k0 = blockIdx.y * 32;
  #pragma unroll
  for (int u = 0; u < 4; u++) {
    int k = i + u * 8;
    tile[k][j] = W[(size_t)(k0 + k) * 1024 + n0 + j];
  }
  __syncthreads();
  #pragma unroll
  for (int u = 0; u < 4; u++) {
    int n = i + u * 8;
    Wt[(size_t)(n0 + n) * 1024 + k0 + j] = (bf16)tile[j][n];
  }
}

// ============================================================
// LayerNorm + modulate -> bf16 (+ optional phi = x1 . doob_w)
// ============================================================
__global__ __launch_bounds__(256) void ln_mod_kernel(const float* __restrict__ xin,
                                                     const float* __restrict__ nsc,
                                                     const float* __restrict__ nbi,
                                                     const float* __restrict__ mod,
                                                     const float* __restrict__ doobw,
                                                     float* __restrict__ phi,
                                                     bf16* __restrict__ outp) {
  int row = blockIdx.x;              // 0..4095
  int b = row >> 11;
  int t = threadIdx.x;
  const float* xr = xin + (size_t)row * 1024;
  float v[4], s = 0.f, ss = 0.f;
  #pragma unroll
  for (int u = 0; u < 4; u++) { v[u] = xr[t + u * 256]; s += v[u]; ss += v[u] * v[u]; }
  #pragma unroll
  for (int off = 1; off < 64; off <<= 1) { s += __shfl_xor(s, off, 64); ss += __shfl_xor(ss, off, 64); }
  __shared__ float sb[4], ssb[4], pb[4];
  if ((t & 63) == 0) { sb[t >> 6] = s; ssb[t >> 6] = ss; }
  __syncthreads();
  s = sb[0] + sb[1] + sb[2] + sb[3];
  ss = ssb[0] + ssb[1] + ssb[2] + ssb[3];
  float mu = s * (1.f / 1024.f);
  float var = ss * (1.f / 1024.f) - mu * mu;
  float rs = rsqrtf(var + 1e-6f);
  const float* shv = mod + b * 4096;
  const float* scv = mod + b * 4096 + 1024;
  float ph = 0.f;
  #pragma unroll
  for (int u = 0; u < 4; u++) {
    int d = t + u * 256;
    float y = (v[u] - mu) * rs * nsc[d] + nbi[d];
    float ym = y * (1.f + scv[d]) + shv[d];
    outp[(size_t)row * 1024 + d] = (bf16)ym;
    if (doobw) ph += ym * doobw[d];
  }
  if (doobw) {
    #pragma unroll
    for (int off = 1; off < 64; off <<= 1) ph += __shfl_xor(ph, off, 64);
    if ((t & 63) == 0) pb[t >> 6] = ph;
    __syncthreads();
    if (t == 0) phi[row] = pb[0] + pb[1] + pb[2] + pb[3];
  }
}

__global__ __launch_bounds__(256) void phimax_kernel(const float* __restrict__ phi,
                                                     float* __restrict__ pm) {
  int b = blockIdx.x;
  int t = threadIdx.x;
  float m = -1e30f;
  #pragma unroll
  for (int u = 0; u < 8; u++) m = fmaxf(m, phi[b * 2048 + t + u * 256]);
  #pragma unroll
  for (int off = 1; off < 64; off <<= 1) m = fmaxf(m, __shfl_xor(m, off, 64));
  __shared__ float mb[4];
  if ((t & 63) == 0) mb[t >> 6] = m;
  __syncthreads();
  if (t == 0) pm[b] = fmaxf(fmaxf(mb[0], mb[1]), fmaxf(mb[2], mb[3]));
}

// ============================================================
// bf16 MFMA GEMM w/ global_load_lds staging, XOR-swizzled LDS (stride 64, no pad)
// TM in {64,128}, N-tile = 128. 2x2 waves.
// MODE 10: token fused out: col<1024 -> qk = val*sca (B,N,D); col>=1024 -> vt (B,H,64,N)
// MODE 11: channel fused:   col<1024 -> qkct = val*scc (B,HC,128,N); col>=1024 -> v (B,N,D)
// MODE 4 : out = resid + val*gate (fp32, B,N,D)
// ============================================================
template <int MODE, int TM>
__global__ __launch_bounds__(256) void gemm_kernel(const bf16* __restrict__ A,
                                                   const bf16* __restrict__ Wt,
                                                   const float* __restrict__ scale,
                                                   const float* __restrict__ resid,
                                                   void* __restrict__ out0,
                                                   void* __restrict__ out1) {
  constexpr int K = 1024;
  constexpr int WM = TM / 2;       // wave rows
  constexpr int IT = WM / 16;      // i tiles per wave
  __shared__ bf16 As[TM * 64];
  __shared__ bf16 Bs[128 * 64];
  const int m0 = blockIdx.x * TM;
  const int n0 = blockIdx.y * 128;
  const int t = threadIdx.x, lane = t & 63, wid = t >> 6;
  const int wy = wid >> 1, wx = wid & 1;
  const int ml = lane & 15, quad = lane >> 4, rq = quad * 4, kq = quad * 8;
  // staging: lane -> (row srow, swizzled source chunk)
  const int srow = lane >> 3;
  const int schunk = (lane & 7) ^ srow;
  const bf16* gA = A  + (size_t)(m0 + wid * (TM / 4) + srow) * K + schunk * 8;
  const bf16* gB = Wt + (size_t)(n0 + wid * 32 + srow) * K + schunk * 8;
  bf16* lA = As + (wid * (TM / 4)) * 64;
  bf16* lB = Bs + (wid * 32) * 64;
  const int mlm = ml & 7;

  f32x4 acc[IT][4] = {};
  for (int k0 = 0; k0 < K; k0 += 64) {
    __syncthreads();
    #pragma unroll
    for (int q = 0; q < TM / 32; q++)
      gl16(gA + (size_t)q * 8 * K + k0, lA + q * 8 * 64);
    #pragma unroll
    for (int q = 0; q < 4; q++)
      gl16(gB + (size_t)q * 8 * K + k0, lB + q * 8 * 64);
    __syncthreads();
    #pragma unroll
    for (int ks = 0; ks < 2; ks++) {
      const int slot = ((ks * 4 + quad) ^ mlm) * 8;
      bf16x8 af[IT], bfv[4];
      #pragma unroll
      for (int i = 0; i < IT; i++)
        af[i] = *(const bf16x8*)(As + (wy * WM + i * 16 + ml) * 64 + slot);
      #pragma unroll
      for (int j = 0; j < 4; j++)
        bfv[j] = *(const bf16x8*)(Bs + (wx * 64 + j * 16 + ml) * 64 + slot);
      #pragma unroll
      for (int i = 0; i < IT; i++)
        #pragma unroll
        for (int j = 0; j < 4; j++)
          acc[i][j] = __builtin_amdgcn_mfma_f32_16x16x32_bf16(af[i], bfv[j], acc[i][j], 0, 0, 0);
    }
  }
  // epilogue
  #pragma unroll
  for (int i = 0; i < IT; i++) {
    #pragma unroll
    for (int j = 0; j < 4; j++) {
      int col = n0 + wx * 64 + j * 16 + ml;
      #pragma unroll
      for (int r = 0; r < 4; r++) {
        int row = m0 + wy * WM + i * 16 + rq + r;
        int b = row >> 11, n = row & 2047;
        float val = acc[i][j][r];
        if constexpr (MODE == 10) {
          if (col < 1024) {
            ((bf16*)out0)[(size_t)row * 1024 + col] = (bf16)(val * scale[b * 1024 + col]);
          } else {
            int c2 = col - 1024;
            ((bf16*)out1)[((size_t)((b * 16 + (c2 >> 6)) * 64 + (c2 & 63))) * 2048 + n] = (bf16)val;
          }
        } else if constexpr (MODE == 11) {
          if (col < 1024) {
            float sv = val * scale[b * 1024 + col];
            ((bf16*)out0)[((size_t)((b * 8 + (col >> 7)) * 128 + (col & 127))) * 2048 + n] = (bf16)sv;
          } else {
            ((bf16*)out1)[(size_t)row * 1024 + (col - 1024)] = (bf16)val;
          }
        } else {
          float g = scale[b * 1024 + col];
          ((float*)out0)[(size_t)row * 1024 + col] =
              resid[(size_t)row * 1024 + col] + val * g;
        }
      }
    }
  }
}

// ============================================================
// q2 per (b,h,n) + e = (phi - q2 - phimax[b]) -- both pre-scaled by log2(e)
// ============================================================
__global__ __launch_bounds__(256) void q2e_kernel(const bf16* __restrict__ qk,
                                                  const float* __restrict__ phi,
                                                  const float* __restrict__ pm,
                                                  float* __restrict__ q2buf,
                                                  float* __restrict__ ebuf) {
  int row = blockIdx.x;              // b*2048+n
  int b = row >> 11, n = row & 2047;
  int t = threadIdx.x;
  const bf16* qr = qk + (size_t)row * 1024;
  __shared__ float q2s[16][17];
  {
    int h = t >> 4, i0 = (t & 15) * 4;
    float q = 0.f;
    #pragma unroll
    for (int u = 0; u < 4; u++) { float qv = (float)qr[h * 64 + i0 + u]; q += qv * qv; }
    q2s[h][t & 15] = q;
  }
  __syncthreads();
  if (t < 16) {
    float q2 = 0.f;
    #pragma unroll
    for (int u = 0; u < 16; u++) q2 += q2s[t][u];
    q2buf[(size_t)(b * 16 + t) * 2048 + n] = q2 * 1.44269504f;
    ebuf [(size_t)(b * 16 + t) * 2048 + n] = (phi[row] - q2 - pm[b]) * 1.44269504f;
  }
}

// ============================================================
// Flash attention, static-max softmax, swapped-operand QK^T.
// grid (16 mtiles, 32 bh); 512 thr = 8 waves; 128 Q-rows/block, wave owns 16.
// S^T = mfma(K,Q) puts a full P row lane-local (q = ml): pack to bf16 with
// v_cvt_pk, 8 dword stores into a wave-private swizzled P strip, b128 reload
// as the PV A-fragment. K/V double-buffered via global_load_lds with
// pre-swizzled source (involution c ^= r&7); one barrier per kv-chunk.
// ============================================================
__global__ __launch_bounds__(512, 4) void flash_kernel(const bf16* __restrict__ qk,  // (B,N,D)
                                                       const bf16* __restrict__ vt,  // (B,H,64,N)
                                                       const float* __restrict__ q2buf,
                                                       const float* __restrict__ ebuf,
                                                       bf16* __restrict__ wout) {    // (B,N,D)
  int mt = blockIdx.x, bh = blockIdx.y;
  int b = bh >> 4, h = bh & 15;
  int m0 = mt * 128;
  int t = threadIdx.x, lane = t & 63, w = t >> 6;     // 8 waves
  int ml = lane & 15, quad = lane >> 4;
  int mlm = ml & 7, q1 = quad & 1, qh = quad >> 1;

  __shared__ __align__(16) bf16 Ks[2][64 * 64];
  __shared__ __align__(16) bf16 Vs[2][64 * 64];
  __shared__ __align__(16) bf16 Ps[8 * 16 * 64];      // per-wave 16x64 P strip

  // staging: each thread owns one 16B K chunk + one 16B V chunk per kv-tile.
  // LDS dest is linear (gl16: wave base + lane*16); source chunk pre-swizzled.
  int sr = lane >> 3, swz = (lane & 7) ^ sr;
  const bf16* gK = qk + (size_t)(b * 2048 + 8 * w + sr) * 1024 + h * 64 + swz * 8;
  const bf16* gV = vt + (size_t)(bh * 64 + 8 * w + sr) * 2048 + swz * 8;

  // Q fragments in registers (loop-invariant); B-operand row = q = w*16+ml
  const bf16* qrow = qk + (size_t)(b * 2048 + m0 + w * 16 + ml) * 1024 + h * 64;
  bf16x8 qf0 = *(const bf16x8*)(qrow + quad * 8);
  bf16x8 qf1 = *(const bf16x8*)(qrow + 32 + quad * 8);

  float q2l = q2buf[(size_t)bh * 2048 + m0 + w * 16 + ml];   // pre-scaled log2e
  const float* ep = ebuf + (size_t)bh * 2048;                // pre-scaled log2e

  bf16* Pb = Ps + (w * 16 + ml) * 64;   // this lane's P row (q = w*16+ml)
  f32x4 oacc[4] = {};
  float rs = 0.f;

  // prologue stage chunk 0 -> buf 0
  gl16(gK, &Ks[0][w * 512]);
  gl16(gV, &Vs[0][w * 512]);

  #pragma unroll 2
  for (int nc = 0; nc < 32; nc++) {
    int cur = nc & 1;
    __syncthreads();                     // drains cur's stage (vmcnt 0) + barrier
    if (nc + 1 < 32) {                   // next chunk flies across this compute
      gl16(gK + (size_t)(nc + 1) * 64 * 1024, &Ks[cur ^ 1][w * 512]);
      gl16(gV + (nc + 1) * 64,                &Vs[cur ^ 1][w * 512]);
    }
    const bf16* Kc = Ks[cur];
    const bf16* Vc = Vs[cur];

    // S^T = K.Q^T : output row = kv-local (quad*4+r+16j), col = q (= ml)
    f32x4 sacc[4] = {};
    __builtin_amdgcn_s_setprio(1);
    #pragma unroll
    for (int ks = 0; ks < 2; ks++) {
      bf16x8 qb = ks ? qf1 : qf0;
      #pragma unroll
      for (int j = 0; j < 4; j++) {
        bf16x8 ka = *(const bf16x8*)(Kc + (j * 16 + ml) * 64 + ((4 * ks + quad) ^ mlm) * 8);
        sacc[j] = __builtin_amdgcn_mfma_f32_16x16x32_bf16(ka, qb, sacc[j], 0, 0, 0);
      }
    }
    __builtin_amdgcn_s_setprio(0);

    // softmax: lane holds P[q=ml][kv = 16j + 4quad + r]; pack pairs, store
    // dwords into the swizzled strip (chunk ^= row&7 — same involution as reads)
    const float* epc = ep + nc * 64;
    #pragma unroll
    for (int j = 0; j < 4; j++) {
      float4 ev = *(const float4*)(epc + j * 16 + quad * 4);
      float p0 = exp2f(fmaf(2.88539008f, sacc[j][0], ev.x - q2l));
      float p1 = exp2f(fmaf(2.88539008f, sacc[j][1], ev.y - q2l));
      float p2 = exp2f(fmaf(2.88539008f, sacc[j][2], ev.z - q2l));
      float p3 = exp2f(fmaf(2.88539008f, sacc[j][3], ev.w - q2l));
      rs += (p0 + p1) + (p2 + p3);
      int sl = (((2 * j + qh) ^ mlm) * 4 + 2 * q1) * 2;    // bf16 idx of dword slot
      *(bf16x2*)(Pb + sl)     = cvt_pk_bf16(p0, p1);
      *(bf16x2*)(Pb + sl + 2) = cvt_pk_bf16(p2, p3);
    }
    // wave-private strip: in-wave DS ordering suffices; fence compiler reorder
    __builtin_amdgcn_sched_barrier(0);

    __builtin_amdgcn_s_setprio(1);
    #pragma unroll
    for (int ks = 0; ks < 2; ks++) {
      bf16x8 pa = *(const bf16x8*)(Pb + ((4 * ks + quad) ^ mlm) * 8);
      #pragma unroll
      for (int jd = 0; jd < 4; jd++) {
        bf16x8 vb = *(const bf16x8*)(Vc + (jd * 16 + ml) * 64 + ((4 * ks + quad) ^ mlm) * 8);
        oacc[jd] = __builtin_amdgcn_mfma_f32_16x16x32_bf16(pa, vb, oacc[jd], 0, 0, 0);
      }
    }
    __builtin_amdgcn_s_setprio(0);
  }

  // row-sum: lane has partial for q = w*16+ml over its kv subset; fold quads
  rs += __shfl_xor(rs, 16, 64);
  rs += __shfl_xor(rs, 32, 64);
  float rinv = 1.f / rs;

  int rq = quad * 4;
  float rv[4];
  #pragma unroll
  for (int r = 0; r < 4; r++) rv[r] = __shfl(rinv, rq + r, 64);

  bf16* wrow = wout + (size_t)(b * 2048 + m0 + w * 16) * 1024 + h * 64;
  #pragma unroll
  for (int jd = 0; jd < 4; jd++)
    #pragma unroll
    for (int r = 0; r < 4; r++)
      wrow[(size_t)(rq + r) * 1024 + jd * 16 + ml] = (bf16)(oacc[jd][r] * rv[r]);
}

// ============================================================
// Channel attention
// ============================================================
// split-K Gram: grid (16 bh, 8 kslice): dotp[(ks*16+bh)][c][d] over 256-deep slice
__global__ __launch_bounds__(256) void gram_kernel(const bf16* __restrict__ qkct,
                                                   float* __restrict__ dotp) {
  int bh = blockIdx.x, ksl = blockIdx.y;
  const bf16* Q = qkct + (size_t)bh * 128 * 2048 + ksl * 256;
  __shared__ bf16 Ts[128 * 40];
  int t = threadIdx.x, lane = t & 63, w = t >> 6;
  int ml = lane & 15, kq = (lane >> 4) * 8, rq = (lane >> 4) * 4;
  f32x4 acc[2][8] = {};
  for (int k0 = 0; k0 < 256; k0 += 32) {
    __syncthreads();
    #pragma unroll
    for (int u = 0; u < 2; u++) {
      int idx = u * 256 + t;                 // 512 units: 128 rows x 4 x 16B
      int r = idx >> 2, seg = (idx & 3) * 8;
      *(uint4*)(Ts + r * 40 + seg) = *(const uint4*)(Q + (size_t)r * 2048 + k0 + seg);
    }
    __syncthreads();
    bf16x8 afr[2], bfr[8];
    #pragma unroll
    for (int i = 0; i < 2; i++) afr[i] = *(const bf16x8*)(Ts + (w * 32 + i * 16 + ml) * 40 + kq);
    #pragma unroll
    for (int j = 0; j < 8; j++) bfr[j] = *(const bf16x8*)(Ts + (j * 16 + ml) * 40 + kq);
    #pragma unroll
    for (int i = 0; i < 2; i++)
      #pragma unroll
      for (int j = 0; j < 8; j++)
        acc[i][j] = __builtin_amdgcn_mfma_f32_16x16x32_bf16(afr[i], bfr[j], acc[i][j], 0, 0, 0);
  }
  float* outp = dotp + ((size_t)ksl * 16 + bh) * 16384;
  #pragma unroll
  for (int i = 0; i < 2; i++)
    #pragma unroll
    for (int j = 0; j < 8; j++)
      #pragma unroll
      for (int r = 0; r < 4; r++) {
        int c = w * 32 + i * 16 + rq + r, d = j * 16 + ml;
        outp[c * 128 + d] = acc[i][j][r];
      }
}

// softmax over d, folding the 8-way partial sum. grid 2048 (bh*128+c), 128 thr.
__global__ __launch_bounds__(128) void chsm_kernel(const float* __restrict__ dotp,
                                                   const float* __restrict__ tau,
                                                   bf16* __restrict__ attnc) {
  int blk = blockIdx.x;
  int bh = blk >> 7, c = blk & 127, hc = bh & 7;
  int d = threadIdx.x;
  float dot = 0.f, dd = 0.f;
  #pragma unroll
  for (int kc = 0; kc < 8; kc++) {
    const float* pp = dotp + ((size_t)kc * 16 + bh) * 16384;
    dot += pp[c * 128 + d];
    dd  += pp[d * 128 + d];
  }
  __shared__ float diag[128];
  __shared__ float red[2], red2[2];
  diag[d] = dd;
  __syncthreads();
  float qc = diag[c];
  float sc = tau[hc] * rsqrtf(2048.f);
  float lg = sc * (2.f * dot - qc - dd);
  float mx = lg;
  #pragma unroll
  for (int off = 1; off < 64; off <<= 1) mx = fmaxf(mx, __shfl_xor(mx, off, 64));
  if ((d & 63) == 0) red[d >> 6] = mx;
  __syncthreads();
  mx = fmaxf(red[0], red[1]);
  float e = exp2f((lg - mx) * 1.44269504f);
  float sm = e;
  #pragma unroll
  for (int off = 1; off < 64; off <<= 1) sm += __shfl_xor(sm, off, 64);
  if ((d & 63) == 0) red2[d >> 6] = sm;
  __syncthreads();
  sm = red2[0] + red2[1];
  attnc[(size_t)bh * 16384 + c * 128 + d] = (bf16)(e / sm);
}

// wc[c][n] = sum_d attnc[c][d] * vc[b][n][hc*128+d]; write wcn (B,N,D)
__global__ __launch_bounds__(256) void chav_kernel(const bf16* __restrict__ attnc,
                                                   const bf16* __restrict__ vc,
                                                   bf16* __restrict__ wcn) {
  int nb = blockIdx.x, bh = blockIdx.y;
  int b = bh >> 3, hc = bh & 7;
  int n0 = nb * 64;
  __shared__ bf16 As[128 * 136];
  __shared__ bf16 Bs[64 * 136];
  int t = threadIdx.x, lane = t & 63, w = t >> 6;
  int ml = lane & 15, kq = (lane >> 4) * 8, rq = (lane >> 4) * 4;
  #pragma unroll
  for (int u = 0; u < 8; u++) {                  // A: 128 rows x 16 x 16B
    int idx = u * 256 + t;
    int r = idx >> 4, seg = (idx & 15) * 8;
    *(uint4*)(As + r * 136 + seg) = *(const uint4*)(attnc + (size_t)bh * 16384 + r * 128 + seg);
  }
  #pragma unroll
  for (int u = 0; u < 4; u++) {                  // B: 64 rows x 16 x 16B
    int idx = u * 256 + t;
    int r = idx >> 4, seg = (idx & 15) * 8;
    *(uint4*)(Bs + r * 136 + seg) =
        *(const uint4*)(vc + (size_t)(b * 2048 + n0 + r) * 1024 + hc * 128 + seg);
  }
  __syncthreads();
  f32x4 acc[2][4] = {};
  #pragma unroll
  for (int ks = 0; ks < 4; ks++) {
    bf16x8 afr[2], bfr[4];
    #pragma unroll
    for (int i = 0; i < 2; i++)
      afr[i] = *(const bf16x8*)(As + (w * 32 + i * 16 + ml) * 136 + ks * 32 + kq);
    #pragma unroll
    for (int j = 0; j < 4; j++)
      bfr[j] = *(const bf16x8*)(Bs + (j * 16 + ml) * 136 + ks * 32 + kq);
    #pragma unroll
    for (int i = 0; i < 2; i++)
      #pragma unroll
      for (int j = 0; j < 4; j++)
        acc[i][j] = __builtin_amdgcn_mfma_f32_16x16x32_bf16(afr[i], bfr[j], acc[i][j], 0, 0, 0);
  }
  #pragma unroll
  for (int i = 0; i < 2; i++)
    #pragma unroll
    for (int j = 0; j < 4; j++)
      #pragma unroll
      for (int r = 0; r < 4; r++) {
        int c = w * 32 + i * 16 + rq + r;
        int n = n0 + j * 16 + ml;
        wcn[(size_t)(b * 2048 + n) * 1024 + hc * 128 + c] = (bf16)acc[i][j][r];
      }
}

// ============================================================
// Host launcher
// ============================================================
extern "C" void kernel_launch(void* const* d_in, const int* in_sizes, int n_in,
                              void* d_out, int out_size, void* d_ws, size_t ws_size,
                              hipStream_t stream) {
  const float* x      = (const float*)d_in[0];
  const float* t      = (const float*)d_in[1];
  const float* n1s    = (const float*)d_in[2];
  const float* n1b    = (const float*)d_in[3];
  const float* n2s    = (const float*)d_in[4];
  const float* n2b    = (const float*)d_in[5];
  const float* tc_w1  = (const float*)d_in[6];
  const float* tc_b1  = (const float*)d_in[7];
  const float* tc_w2  = (const float*)d_in[8];
  const float* tc_b2  = (const float*)d_in[9];
  const float* tc_wa  = (const float*)d_in[10];
  const float* tc_ba  = (const float*)d_in[11];
  const float* tc_wc  = (const float*)d_in[12];
  const float* tc_bc  = (const float*)d_in[13];
  const float* aqk_w  = (const float*)d_in[14];
  const float* av_w   = (const float*)d_in[15];
  const float* aout_w = (const float*)d_in[16];
  const float* doobw  = (const float*)d_in[17];
  const float* cqk_w  = (const float*)d_in[19];
  const float* cv_w   = (const float*)d_in[20];
  const float* cout_w = (const float*)d_in[21];
  const float* tau    = (const float*)d_in[22];
  const float* g1     = (const float*)d_in[23];
  const float* g2     = (const float*)d_in[24];
  float* out = (float*)d_out;

  char* p = (char*)d_ws;
  auto alloc = [&](size_t bytes) -> void* {
    void* r = (void*)p;
    p += (bytes + 255) & ~(size_t)255;
    return r;
  };
  float* emb   = (float*)alloc(2 * 4096 * 4);
  float* h1    = (float*)alloc(2 * 4096 * 4);
  float* h2    = (float*)alloc(2 * 4096 * 4);
  float* avec  = (float*)alloc(2 * 4096 * 4);
  float* cvec  = (float*)alloc(2 * 4096 * 4);
  float* sca   = (float*)alloc(2 * 1024 * 4);
  float* scc   = (float*)alloc(2 * 1024 * 4);
  float* agv   = (float*)alloc(2 * 1024 * 4);
  float* cgv   = (float*)alloc(2 * 1024 * 4);
  float* phi   = (float*)alloc(4096 * 4);
  float* pmax  = (float*)alloc(2 * 4);
  float* q2buf = (float*)alloc(2 * 16 * 2048 * 4);
  float* ebuf  = (float*)alloc(2 * 16 * 2048 * 4);
  float* dotp  = (float*)alloc((size_t)8 * 16 * 16384 * 4);
  bf16* attnc  = (bf16*)alloc(16 * 128 * 128 * 2);
  bf16* wt     = (bf16*)alloc((size_t)6 * 1024 * 1024 * 2);
  bf16* xbf    = (bf16*)alloc((size_t)M_ * 1024 * 2);
  bf16* qkbf   = (bf16*)alloc((size_t)M_ * 1024 * 2);
  bf16* vbuf   = (bf16*)alloc((size_t)M_ * 1024 * 2);
  bf16* wbuf   = (bf16*)alloc((size_t)M_ * 1024 * 2);
  (void)ws_size; (void)in_sizes; (void)n_in; (void)out_size;

  // gemv partials (64 slices x 2 rows x 4096 = 2 MB each) alias onto dotp:
  // stage A completes before gram_kernel first writes dotp (stream-ordered).
  float* partA = dotp;
  float* partB = dotp + (size_t)64 * 2 * 4096;

  // concatenated (N x K) weights: token [qk; v] (2048x1024), channel [cqk; cv]
  bf16* wt_tok  = wt;                              // 2048 x 1024
  bf16* wt_out  = wt + (size_t)2 * 1048576;        // 1024 x 1024
  bf16* wt_ch   = wt + (size_t)3 * 1048576;        // 2048 x 1024
  bf16* wt_cout = wt + (size_t)5 * 1048576;        // 1024 x 1024

  dim3 blk(256);
  wtconv6_kernel<<<dim3(32, 32, 6), blk, 0, stream>>>(
      aqk_w, av_w, aout_w, cqk_w, cv_w, cout_w,
      wt_tok, wt_tok + (size_t)1048576, wt_out,
      wt_ch,  wt_ch  + (size_t)1048576, wt_cout);

  // --- stage A: time conditioning ---
  emb_kernel<<<32, blk, 0, stream>>>(t, emb);
  gemv_kernel<<<dim3(8, 64), blk, 0, stream>>>(emb, tc_w1, partA);
  gemv_reduce_kernel<<<32, blk, 0, stream>>>(partA, tc_b1, h1, 1);
  gemv_kernel<<<dim3(8, 64), blk, 0, stream>>>(h1, tc_w2, partA);
  gemv_reduce_kernel<<<32, blk, 0, stream>>>(partA, tc_b2, h2, 1);
  gemv_kernel<<<dim3(8, 64), blk, 0, stream>>>(h2, tc_wa, partA);
  gemv_kernel<<<dim3(8, 64), blk, 0, stream>>>(h2, tc_wc, partB);
  gemv_reduce_kernel<<<32, blk, 0, stream>>>(partA, tc_ba, avec, 0);
  gemv_reduce_kernel<<<32, blk, 0, stream>>>(partB, tc_bc, cvec, 0);
  postA_kernel<<<8, blk, 0, stream>>>(avec, cvec, g1, g2, sca, scc, agv, cgv);

  // --- token attention ---
  ln_mod_kernel<<<4096, blk, 0, stream>>>(x, n1s, n1b, avec, doobw, phi, xbf);
  phimax_kernel<<<2, blk, 0, stream>>>(phi, pmax);
  gemm_kernel<10, 128><<<dim3(32, 16), blk, 0, stream>>>(xbf, wt_tok, sca, nullptr, qkbf, vbuf);
  q2e_kernel<<<4096, blk, 0, stream>>>(qkbf, phi, pmax, q2buf, ebuf);
  flash_kernel<<<dim3(16, 32), dim3(512), 0, stream>>>(qkbf, vbuf, q2buf, ebuf, wbuf);
  gemm_kernel<4, 64><<<dim3(64, 8), blk, 0, stream>>>(wbuf, wt_out, agv, x, out, nullptr);

  // --- channel attention ---
  ln_mod_kernel<<<4096, blk, 0, stream>>>(out, n2s, n2b, cvec, nullptr, nullptr, xbf);
  gemm_kernel<11, 128><<<dim3(32, 16), blk, 0, stream>>>(xbf, wt_ch, scc, nullptr, qkbf, vbuf);
  gram_kernel<<<dim3(16, 8), blk, 0, stream>>>(qkbf, dotp);
  chsm_kernel<<<2048, dim3(128), 0, stream>>>(dotp, tau, attnc);
  chav_kernel<<<dim3(32, 16), blk, 0, stream>>>(attnc, vbuf, wbuf);
  gemm_kernel<4, 64><<<dim3(64, 8), blk, 0, stream>>>(wbuf, wt_cout, cgv, out, out, nullptr);
}

// Round 2
// 576.577 us; speedup vs baseline: 1.1153x; 1.1153x over previous
//
#include <hip/hip_runtime.h>
#include <hip/hip_bf16.h>
#include <math.h>

typedef __bf16 bf16;
typedef bf16 bf16x8 __attribute__((ext_vector_type(8)));
typedef bf16 bf16x2 __attribute__((ext_vector_type(2)));
typedef float f32x4 __attribute__((ext_vector_type(4)));

#define B_   2
#define N_   2048
#define D_   1024
#define H_   16
#define HC_  8
#define M_   (B_*N_)   // 4096 rows in all big GEMMs

// async global->LDS 16B: lds dest = wave-uniform base + lane*16
__device__ __forceinline__ void gl16(const bf16* g, bf16* lds_base) {
#if __has_builtin(__builtin_amdgcn_global_load_lds)
  __builtin_amdgcn_global_load_lds((const __attribute__((address_space(1))) void*)g,
                                   (__attribute__((address_space(3))) void*)lds_base,
                                   16, 0, 0);
#else
  int lane = threadIdx.x & 63;
  *(uint4*)(lds_base + lane * 8) = *(const uint4*)g;
#endif
}

// packed f32 pair -> bf16x2 (RNE), single instruction
__device__ __forceinline__ bf16x2 cvt_pk_bf16(float lo, float hi) {
  unsigned int r;
  asm("v_cvt_pk_bf16_f32 %0, %1, %2" : "=v"(r) : "v"(lo), "v"(hi));
  union { unsigned int u; bf16x2 v; } c;
  c.u = r;
  return c.v;
}

// ============================================================
// Stage A: time-conditioning MLP (GEMV, B=2 rows)
// ============================================================
__global__ __launch_bounds__(256) void emb_kernel(const float* __restrict__ tin,
                                                  float* __restrict__ emb) {
  int idx = blockIdx.x * 256 + threadIdx.x;   // 0..8191
  int b = idx >> 12, p = idx & 4095;
  float tv = tin[b];
  int half = p & 2047;
  float freq = expf(-logf(10000.f) * (float)half * (1.f / 2048.f));
  float arg = tv * freq;
  emb[idx] = (p < 2048) ? cosf(arg) : sinf(arg);
}

__global__ __launch_bounds__(256) void gemv_kernel(const float* __restrict__ x,
                                                   const float* __restrict__ W,
                                                   float* __restrict__ part) {
  __shared__ float xs[2][128];
  int t = threadIdx.x;
  int j0 = blockIdx.x * 512;
  int k0 = blockIdx.y * 128;
  if (t < 128) xs[0][t] = x[k0 + t];
  else         xs[1][t - 128] = x[4096 + k0 + (t - 128)];
  __syncthreads();
  float a00 = 0.f, a01 = 0.f, a10 = 0.f, a11 = 0.f;
  int j = j0 + t * 2;
  #pragma unroll 8
  for (int k = 0; k < 128; k++) {
    float2 wv = *(const float2*)(W + (size_t)(k0 + k) * 4096 + j);
    float x0 = xs[0][k], x1 = xs[1][k];
    a00 += x0 * wv.x; a01 += x0 * wv.y;
    a10 += x1 * wv.x; a11 += x1 * wv.y;
  }
  *(float2*)(part + (size_t)(blockIdx.y * 2 + 0) * 4096 + j) = make_float2(a00, a01);
  *(float2*)(part + (size_t)(blockIdx.y * 2 + 1) * 4096 + j) = make_float2(a10, a11);
}

__global__ __launch_bounds__(256) void gemv_reduce_kernel(const float* __restrict__ part,
                                                          const float* __restrict__ bias,
                                                          float* __restrict__ y, int act) {
  int idx = blockIdx.x * 256 + threadIdx.x;   // 0..8191
  int b = idx >> 12, j = idx & 4095;
  float s = bias[j];
  #pragma unroll
  for (int kc = 0; kc < 32; kc++) s += part[(size_t)(kc * 2 + b) * 4096 + j];
  if (act) s = s / (1.f + expf(-s));          // silu
  y[idx] = s;
}

__global__ __launch_bounds__(256) void postA_kernel(const float* __restrict__ avec,
                                                    const float* __restrict__ cvec,
                                                    const float* __restrict__ g1,
                                                    const float* __restrict__ g2,
                                                    float* __restrict__ sca, float* __restrict__ scc,
                                                    float* __restrict__ agv, float* __restrict__ cgv) {
  int idx = blockIdx.x * 256 + threadIdx.x;   // 0..2047
  int b = idx >> 10, d = idx & 1023;
  sca[idx] = expf(avec[b * 4096 + 3072 + d]);
  scc[idx] = expf(cvec[b * 4096 + 3072 + d]);
  agv[idx] = avec[b * 4096 + 2048 + d] * g1[d];
  cgv[idx] = cvec[b * 4096 + 2048 + d] * g2[d];
}

// ============================================================
// Weight fp32 (K x N) -> bf16 transposed (N x K), 6 weights in one launch
// ============================================================
__global__ __launch_bounds__(256) void wtconv6_kernel(const float* w0, const float* w1,
                                                      const float* w2, const float* w3,
                                                      const float* w4, const float* w5,
                                                      bf16* o0, bf16* o1, bf16* o2,
                                                      bf16* o3, bf16* o4, bf16* o5) {
  const float* W; bf16* Wt;
  switch (blockIdx.z) {
    case 0: W = w0; Wt = o0; break;
    case 1: W = w1; Wt = o1; break;
    case 2: W = w2; Wt = o2; break;
    case 3: W = w3; Wt = o3; break;
    case 4: W = w4; Wt = o4; break;
    default: W = w5; Wt = o5; break;
  }
  __shared__ float tile[32][33];
  int t = threadIdx.x;
  int i = t >> 5, j = t & 31;
  int n0 = blockIdx.x * 32, k0 = blockIdx.y * 32;
  #pragma unroll
  for (int u = 0; u < 4; u++) {
    int k = i + u * 8;
    tile[k][j] = W[(size_t)(k0 + k) * 1024 + n0 + j];
  }
  __syncthreads();
  #pragma unroll
  for (int u = 0; u < 4; u++) {
    int n = i + u * 8;
    Wt[(size_t)(n0 + n) * 1024 + k0 + j] = (bf16)tile[j][n];
  }
}

// ============================================================
// LayerNorm + modulate -> bf16 (+ optional phi = x1 . doob_w)
// ============================================================
__global__ __launch_bounds__(256) void ln_mod_kernel(const float* __restrict__ xin,
                                                     const float* __restrict__ nsc,
                                                     const float* __restrict__ nbi,
                                                     const float* __restrict__ mod,
                                                     const float* __restrict__ doobw,
                                                     float* __restrict__ phi,
                                                     bf16* __restrict__ outp) {
  int row = blockIdx.x;              // 0..4095
  int b = row >> 11;
  int t = threadIdx.x;
  const float* xr = xin + (size_t)row * 1024;
  float v[4], s = 0.f, ss = 0.f;
  #pragma unroll
  for (int u = 0; u < 4; u++) { v[u] = xr[t + u * 256]; s += v[u]; ss += v[u] * v[u]; }
  #pragma unroll
  for (int off = 1; off < 64; off <<= 1) { s += __shfl_xor(s, off, 64); ss += __shfl_xor(ss, off, 64); }
  __shared__ float sb[4], ssb[4], pb[4];
  if ((t & 63) == 0) { sb[t >> 6] = s; ssb[t >> 6] = ss; }
  __syncthreads();
  s = sb[0] + sb[1] + sb[2] + sb[3];
  ss = ssb[0] + ssb[1] + ssb[2] + ssb[3];
  float mu = s * (1.f / 1024.f);
  float var = ss * (1.f / 1024.f) - mu * mu;
  float rs = rsqrtf(var + 1e-6f);
  const float* shv = mod + b * 4096;
  const float* scv = mod + b * 4096 + 1024;
  float ph = 0.f;
  #pragma unroll
  for (int u = 0; u < 4; u++) {
    int d = t + u * 256;
    float y = (v[u] - mu) * rs * nsc[d] + nbi[d];
    float ym = y * (1.f + scv[d]) + shv[d];
    outp[(size_t)row * 1024 + d] = (bf16)ym;
    if (doobw) ph += ym * doobw[d];
  }
  if (doobw) {
    #pragma unroll
    for (int off = 1; off < 64; off <<= 1) ph += __shfl_xor(ph, off, 64);
    if ((t & 63) == 0) pb[t >> 6] = ph;
    __syncthreads();
    if (t == 0) phi[row] = pb[0] + pb[1] + pb[2] + pb[3];
  }
}

__global__ __launch_bounds__(256) void phimax_kernel(const float* __restrict__ phi,
                                                     float* __restrict__ pm) {
  int b = blockIdx.x;
  int t = threadIdx.x;
  float m = -1e30f;
  #pragma unroll
  for (int u = 0; u < 8; u++) m = fmaxf(m, phi[b * 2048 + t + u * 256]);
  #pragma unroll
  for (int off = 1; off < 64; off <<= 1) m = fmaxf(m, __shfl_xor(m, off, 64));
  __shared__ float mb[4];
  if ((t & 63) == 0) mb[t >> 6] = m;
  __syncthreads();
  if (t == 0) pm[b] = fmaxf(fmaxf(mb[0], mb[1]), fmaxf(mb[2], mb[3]));
}

// ============================================================
// bf16 MFMA GEMM w/ global_load_lds staging, XOR-swizzled LDS (stride 64, no pad)
// TM in {64,128}, N-tile = 128. 2x2 waves.
// MODE 10: token fused out: col<1024 -> qkh = val*sca, head-major (B,H,N,64);
//          col>=1024 -> vtb chunk-blocked (B,H,32nc,64dh,64n)   [contiguous
//          8KB K/V chunks for flash DRAM/L2 locality]
// MODE 11: channel fused:   col<1024 -> qkct = val*scc (B,HC,128,N); col>=1024 -> v (B,N,D)
// MODE 4 : out = resid + val*gate (fp32, B,N,D)
// ============================================================
template <int MODE, int TM>
__global__ __launch_bounds__(256) void gemm_kernel(const bf16* __restrict__ A,
                                                   const bf16* __restrict__ Wt,
                                                   const float* __restrict__ scale,
                                                   const float* __restrict__ resid,
                                                   void* __restrict__ out0,
                                                   void* __restrict__ out1) {
  constexpr int K = 1024;
  constexpr int WM = TM / 2;       // wave rows
  constexpr int IT = WM / 16;      // i tiles per wave
  __shared__ bf16 As[TM * 64];
  __shared__ bf16 Bs[128 * 64];
  const int m0 = blockIdx.x * TM;
  const int n0 = blockIdx.y * 128;
  const int t = threadIdx.x, lane = t & 63, wid = t >> 6;
  const int wy = wid >> 1, wx = wid & 1;
  const int ml = lane & 15, quad = lane >> 4, rq = quad * 4, kq = quad * 8;
  // staging: lane -> (row srow, swizzled source chunk)
  const int srow = lane >> 3;
  const int schunk = (lane & 7) ^ srow;
  const bf16* gA = A  + (size_t)(m0 + wid * (TM / 4) + srow) * K + schunk * 8;
  const bf16* gB = Wt + (size_t)(n0 + wid * 32 + srow) * K + schunk * 8;
  bf16* lA = As + (wid * (TM / 4)) * 64;
  bf16* lB = Bs + (wid * 32) * 64;
  const int mlm = ml & 7;

  f32x4 acc[IT][4] = {};
  for (int k0 = 0; k0 < K; k0 += 64) {
    __syncthreads();
    #pragma unroll
    for (int q = 0; q < TM / 32; q++)
      gl16(gA + (size_t)q * 8 * K + k0, lA + q * 8 * 64);
    #pragma unroll
    for (int q = 0; q < 4; q++)
      gl16(gB + (size_t)q * 8 * K + k0, lB + q * 8 * 64);
    __syncthreads();
    #pragma unroll
    for (int ks = 0; ks < 2; ks++) {
      const int slot = ((ks * 4 + quad) ^ mlm) * 8;
      bf16x8 af[IT], bfv[4];
      #pragma unroll
      for (int i = 0; i < IT; i++)
        af[i] = *(const bf16x8*)(As + (wy * WM + i * 16 + ml) * 64 + slot);
      #pragma unroll
      for (int j = 0; j < 4; j++)
        bfv[j] = *(const bf16x8*)(Bs + (wx * 64 + j * 16 + ml) * 64 + slot);
      #pragma unroll
      for (int i = 0; i < IT; i++)
        #pragma unroll
        for (int j = 0; j < 4; j++)
          acc[i][j] = __builtin_amdgcn_mfma_f32_16x16x32_bf16(af[i], bfv[j], acc[i][j], 0, 0, 0);
    }
  }
  // epilogue
  #pragma unroll
  for (int i = 0; i < IT; i++) {
    #pragma unroll
    for (int j = 0; j < 4; j++) {
      int col = n0 + wx * 64 + j * 16 + ml;
      #pragma unroll
      for (int r = 0; r < 4; r++) {
        int row = m0 + wy * WM + i * 16 + rq + r;
        int b = row >> 11, n = row & 2047;
        float val = acc[i][j][r];
        if constexpr (MODE == 10) {
          if (col < 1024) {
            int h = col >> 6, dh = col & 63;
            ((bf16*)out0)[((size_t)(b * 16 + h) * 2048 + n) * 64 + dh] =
                (bf16)(val * scale[b * 1024 + col]);
          } else {
            int c2 = col - 1024;
            int h = c2 >> 6, dh = c2 & 63;
            ((bf16*)out1)[(((size_t)(b * 16 + h) * 32 + (n >> 6)) * 64 + dh) * 64 + (n & 63)] =
                (bf16)val;
          }
        } else if constexpr (MODE == 11) {
          if (col < 1024) {
            float sv = val * scale[b * 1024 + col];
            ((bf16*)out0)[((size_t)((b * 8 + (col >> 7)) * 128 + (col & 127))) * 2048 + n] = (bf16)sv;
          } else {
            ((bf16*)out1)[(size_t)row * 1024 + (col - 1024)] = (bf16)val;
          }
        } else {
          float g = scale[b * 1024 + col];
          ((float*)out0)[(size_t)row * 1024 + col] =
              resid[(size_t)row * 1024 + col] + val * g;
        }
      }
    }
  }
}

// ============================================================
// q2 per (b,h,n) + e = (phi - q2 - phimax[b]) -- both pre-scaled by log2(e)
// head-major qkh input: one thread per (bh,n) row, 64 contiguous bf16.
// ============================================================
__global__ __launch_bounds__(256) void q2e_kernel(const bf16* __restrict__ qkh,
                                                  const float* __restrict__ phi,
                                                  const float* __restrict__ pm,
                                                  float* __restrict__ q2buf,
                                                  float* __restrict__ ebuf) {
  int idx = blockIdx.x * 256 + threadIdx.x;   // 0..65535 = bh*2048 + n
  int bh = idx >> 11, n = idx & 2047;
  int b = bh >> 4;
  const bf16* qr = qkh + (size_t)idx * 64;
  float q = 0.f;
  #pragma unroll
  for (int u = 0; u < 8; u++) {
    bf16x8 v = *(const bf16x8*)(qr + u * 8);
    #pragma unroll
    for (int e = 0; e < 8; e++) { float f = (float)v[e]; q += f * f; }
  }
  q2buf[idx] = q * 1.44269504f;
  ebuf[idx]  = (phi[b * 2048 + n] - q - pm[b]) * 1.44269504f;
}

// ============================================================
// Flash attention, static-max softmax, swapped-operand QK^T.
// grid (16 mtiles, 32 bh); 512 thr = 8 waves; 128 Q-rows/block, wave owns 16.
// Operands head-major: qkh (B,H,N,64) and vtb (B,H,nc,64,64) give contiguous
// 8KB K/V chunk stages (DRAM row locality + full L2-line use).
// S^T = mfma(K,Q) puts a full P row lane-local (q = ml): pack to bf16 with
// v_cvt_pk, 8 dword stores into a wave-private swizzled P strip, b128 reload
// as the PV A-fragment. K/V double-buffered via global_load_lds with
// pre-swizzled source (involution c ^= r&7); one barrier per kv-chunk.
// ============================================================
__global__ __launch_bounds__(512, 4) void flash_kernel(const bf16* __restrict__ qkh,  // (B,H,N,64)
                                                       const bf16* __restrict__ vtb,  // (B,H,32,64,64)
                                                       const float* __restrict__ q2buf,
                                                       const float* __restrict__ ebuf,
                                                       bf16* __restrict__ wout) {     // (B,N,D)
  int mt = blockIdx.x, bh = blockIdx.y;
  int b = bh >> 4, h = bh & 15;
  int m0 = mt * 128;
  int t = threadIdx.x, lane = t & 63, w = t >> 6;     // 8 waves
  int ml = lane & 15, quad = lane >> 4;
  int mlm = ml & 7, q1 = quad & 1, qh = quad >> 1;

  __shared__ __align__(16) bf16 Ks[2][64 * 64];
  __shared__ __align__(16) bf16 Vs[2][64 * 64];
  __shared__ __align__(16) bf16 Ps[8 * 16 * 64];      // per-wave 16x64 P strip

  // staging: each thread owns one 16B K chunk + one 16B V chunk per kv-tile.
  // LDS dest is linear (gl16: wave base + lane*16); source chunk pre-swizzled.
  int sr = lane >> 3, swz = (lane & 7) ^ sr;
  const bf16* gK = qkh + ((size_t)bh * 2048 + 8 * w + sr) * 64 + swz * 8;
  const bf16* gV = vtb + (size_t)bh * 32 * 4096 + (8 * w + sr) * 64 + swz * 8;

  // Q fragments in registers (loop-invariant); B-operand row = q = w*16+ml
  const bf16* qrow = qkh + ((size_t)bh * 2048 + m0 + w * 16 + ml) * 64;
  bf16x8 qf0 = *(const bf16x8*)(qrow + quad * 8);
  bf16x8 qf1 = *(const bf16x8*)(qrow + 32 + quad * 8);

  float q2l = q2buf[(size_t)bh * 2048 + m0 + w * 16 + ml];   // pre-scaled log2e
  const float* ep = ebuf + (size_t)bh * 2048;                // pre-scaled log2e

  bf16* Pb = Ps + (w * 16 + ml) * 64;   // this lane's P row (q = w*16+ml)
  f32x4 oacc[4] = {};
  float rs = 0.f;

  // prologue stage chunk 0 -> buf 0
  gl16(gK, &Ks[0][w * 512]);
  gl16(gV, &Vs[0][w * 512]);

  #pragma unroll 2
  for (int nc = 0; nc < 32; nc++) {
    int cur = nc & 1;
    __syncthreads();                     // drains cur's stage (vmcnt 0) + barrier
    if (nc + 1 < 32) {                   // next chunk flies across this compute
      gl16(gK + (size_t)(nc + 1) * 4096, &Ks[cur ^ 1][w * 512]);
      gl16(gV + (size_t)(nc + 1) * 4096, &Vs[cur ^ 1][w * 512]);
    }
    const bf16* Kc = Ks[cur];
    const bf16* Vc = Vs[cur];

    // S^T = K.Q^T : output row = kv-local (quad*4+r+16j), col = q (= ml)
    f32x4 sacc[4] = {};
    __builtin_amdgcn_s_setprio(1);
    #pragma unroll
    for (int ks = 0; ks < 2; ks++) {
      bf16x8 qb = ks ? qf1 : qf0;
      #pragma unroll
      for (int j = 0; j < 4; j++) {
        bf16x8 ka = *(const bf16x8*)(Kc + (j * 16 + ml) * 64 + ((4 * ks + quad) ^ mlm) * 8);
        sacc[j] = __builtin_amdgcn_mfma_f32_16x16x32_bf16(ka, qb, sacc[j], 0, 0, 0);
      }
    }
    __builtin_amdgcn_s_setprio(0);

    // softmax: lane holds P[q=ml][kv = 16j + 4quad + r]; pack pairs, store
    // dwords into the swizzled strip (chunk ^= row&7 — same involution as reads)
    const float* epc = ep + nc * 64;
    #pragma unroll
    for (int j = 0; j < 4; j++) {
      float4 ev = *(const float4*)(epc + j * 16 + quad * 4);
      float p0 = exp2f(fmaf(2.88539008f, sacc[j][0], ev.x - q2l));
      float p1 = exp2f(fmaf(2.88539008f, sacc[j][1], ev.y - q2l));
      float p2 = exp2f(fmaf(2.88539008f, sacc[j][2], ev.z - q2l));
      float p3 = exp2f(fmaf(2.88539008f, sacc[j][3], ev.w - q2l));
      rs += (p0 + p1) + (p2 + p3);
      int sl = (((2 * j + qh) ^ mlm) * 4 + 2 * q1) * 2;    // bf16 idx of dword slot
      *(bf16x2*)(Pb + sl)     = cvt_pk_bf16(p0, p1);
      *(bf16x2*)(Pb + sl + 2) = cvt_pk_bf16(p2, p3);
    }
    // wave-private strip: in-wave DS ordering suffices; fence compiler reorder
    __builtin_amdgcn_sched_barrier(0);

    __builtin_amdgcn_s_setprio(1);
    #pragma unroll
    for (int ks = 0; ks < 2; ks++) {
      bf16x8 pa = *(const bf16x8*)(Pb + ((4 * ks + quad) ^ mlm) * 8);
      #pragma unroll
      for (int jd = 0; jd < 4; jd++) {
        bf16x8 vb = *(const bf16x8*)(Vc + (jd * 16 + ml) * 64 + ((4 * ks + quad) ^ mlm) * 8);
        oacc[jd] = __builtin_amdgcn_mfma_f32_16x16x32_bf16(pa, vb, oacc[jd], 0, 0, 0);
      }
    }
    __builtin_amdgcn_s_setprio(0);
  }

  // row-sum: lane has partial for q = w*16+ml over its kv subset; fold quads
  rs += __shfl_xor(rs, 16, 64);
  rs += __shfl_xor(rs, 32, 64);
  float rinv = 1.f / rs;

  int rq = quad * 4;
  float rv[4];
  #pragma unroll
  for (int r = 0; r < 4; r++) rv[r] = __shfl(rinv, rq + r, 64);

  bf16* wrow = wout + (size_t)(b * 2048 + m0 + w * 16) * 1024 + h * 64;
  #pragma unroll
  for (int jd = 0; jd < 4; jd++)
    #pragma unroll
    for (int r = 0; r < 4; r++)
      wrow[(size_t)(rq + r) * 1024 + jd * 16 + ml] = (bf16)(oacc[jd][r] * rv[r]);
}

// ============================================================
// Channel attention
// ============================================================
// split-K Gram: grid (16 bh, 8 kslice): dotp[(ks*16+bh)][c][d] over 256-deep slice
__global__ __launch_bounds__(256) void gram_kernel(const bf16* __restrict__ qkct,
                                                   float* __restrict__ dotp) {
  int bh = blockIdx.x, ksl = blockIdx.y;
  const bf16* Q = qkct + (size_t)bh * 128 * 2048 + ksl * 256;
  __shared__ bf16 Ts[128 * 40];
  int t = threadIdx.x, lane = t & 63, w = t >> 6;
  int ml = lane & 15, kq = (lane >> 4) * 8, rq = (lane >> 4) * 4;
  f32x4 acc[2][8] = {};
  for (int k0 = 0; k0 < 256; k0 += 32) {
    __syncthreads();
    #pragma unroll
    for (int u = 0; u < 2; u++) {
      int idx = u * 256 + t;                 // 512 units: 128 rows x 4 x 16B
      int r = idx >> 2, seg = (idx & 3) * 8;
      *(uint4*)(Ts + r * 40 + seg) = *(const uint4*)(Q + (size_t)r * 2048 + k0 + seg);
    }
    __syncthreads();
    bf16x8 afr[2], bfr[8];
    #pragma unroll
    for (int i = 0; i < 2; i++) afr[i] = *(const bf16x8*)(Ts + (w * 32 + i * 16 + ml) * 40 + kq);
    #pragma unroll
    for (int j = 0; j < 8; j++) bfr[j] = *(const bf16x8*)(Ts + (j * 16 + ml) * 40 + kq);
    #pragma unroll
    for (int i = 0; i < 2; i++)
      #pragma unroll
      for (int j = 0; j < 8; j++)
        acc[i][j] = __builtin_amdgcn_mfma_f32_16x16x32_bf16(afr[i], bfr[j], acc[i][j], 0, 0, 0);
  }
  float* outp = dotp + ((size_t)ksl * 16 + bh) * 16384;
  #pragma unroll
  for (int i = 0; i < 2; i++)
    #pragma unroll
    for (int j = 0; j < 8; j++)
      #pragma unroll
      for (int r = 0; r < 4; r++) {
        int c = w * 32 + i * 16 + rq + r, d = j * 16 + ml;
        outp[c * 128 + d] = acc[i][j][r];
      }
}

// softmax over d, folding the 8-way partial sum. grid 2048 (bh*128+c), 128 thr.
__global__ __launch_bounds__(128) void chsm_kernel(const float* __restrict__ dotp,
                                                   const float* __restrict__ tau,
                                                   bf16* __restrict__ attnc) {
  int blk = blockIdx.x;
  int bh = blk >> 7, c = blk & 127, hc = bh & 7;
  int d = threadIdx.x;
  float dot = 0.f, dd = 0.f;
  #pragma unroll
  for (int kc = 0; kc < 8; kc++) {
    const float* pp = dotp + ((size_t)kc * 16 + bh) * 16384;
    dot += pp[c * 128 + d];
    dd  += pp[d * 128 + d];
  }
  __shared__ float diag[128];
  __shared__ float red[2], red2[2];
  diag[d] = dd;
  __syncthreads();
  float qc = diag[c];
  float sc = tau[hc] * rsqrtf(2048.f);
  float lg = sc * (2.f * dot - qc - dd);
  float mx = lg;
  #pragma unroll
  for (int off = 1; off < 64; off <<= 1) mx = fmaxf(mx, __shfl_xor(mx, off, 64));
  if ((d & 63) == 0) red[d >> 6] = mx;
  __syncthreads();
  mx = fmaxf(red[0], red[1]);
  float e = exp2f((lg - mx) * 1.44269504f);
  float sm = e;
  #pragma unroll
  for (int off = 1; off < 64; off <<= 1) sm += __shfl_xor(sm, off, 64);
  if ((d & 63) == 0) red2[d >> 6] = sm;
  __syncthreads();
  sm = red2[0] + red2[1];
  attnc[(size_t)bh * 16384 + c * 128 + d] = (bf16)(e / sm);
}

// wc[c][n] = sum_d attnc[c][d] * vc[b][n][hc*128+d]; write wcn (B,N,D)
__global__ __launch_bounds__(256) void chav_kernel(const bf16* __restrict__ attnc,
                                                   const bf16* __restrict__ vc,
                                                   bf16* __restrict__ wcn) {
  int nb = blockIdx.x, bh = blockIdx.y;
  int b = bh >> 3, hc = bh & 7;
  int n0 = nb * 64;
  __shared__ bf16 As[128 * 136];
  __shared__ bf16 Bs[64 * 136];
  int t = threadIdx.x, lane = t & 63, w = t >> 6;
  int ml = lane & 15, kq = (lane >> 4) * 8, rq = (lane >> 4) * 4;
  #pragma unroll
  for (int u = 0; u < 8; u++) {                  // A: 128 rows x 16 x 16B
    int idx = u * 256 + t;
    int r = idx >> 4, seg = (idx & 15) * 8;
    *(uint4*)(As + r * 136 + seg) = *(const uint4*)(attnc + (size_t)bh * 16384 + r * 128 + seg);
  }
  #pragma unroll
  for (int u = 0; u < 4; u++) {                  // B: 64 rows x 16 x 16B
    int idx = u * 256 + t;
    int r = idx >> 4, seg = (idx & 15) * 8;
    *(uint4*)(Bs + r * 136 + seg) =
        *(const uint4*)(vc + (size_t)(b * 2048 + n0 + r) * 1024 + hc * 128 + seg);
  }
  __syncthreads();
  f32x4 acc[2][4] = {};
  #pragma unroll
  for (int ks = 0; ks < 4; ks++) {
    bf16x8 afr[2], bfr[4];
    #pragma unroll
    for (int i = 0; i < 2; i++)
      afr[i] = *(const bf16x8*)(As + (w * 32 + i * 16 + ml) * 136 + ks * 32 + kq);
    #pragma unroll
    for (int j = 0; j < 4; j++)
      bfr[j] = *(const bf16x8*)(Bs + (j * 16 + ml) * 136 + ks * 32 + kq);
    #pragma unroll
    for (int i = 0; i < 2; i++)
      #pragma unroll
      for (int j = 0; j < 4; j++)
        acc[i][j] = __builtin_amdgcn_mfma_f32_16x16x32_bf16(afr[i], bfr[j], acc[i][j], 0, 0, 0);
  }
  #pragma unroll
  for (int i = 0; i < 2; i++)
    #pragma unroll
    for (int j = 0; j < 4; j++)
      #pragma unroll
      for (int r = 0; r < 4; r++) {
        int c = w * 32 + i * 16 + rq + r;
        int n = n0 + j * 16 + ml;
        wcn[(size_t)(b * 2048 + n) * 1024 + hc * 128 + c] = (bf16)acc[i][j][r];
      }
}

// ============================================================
// Host launcher
// ============================================================
extern "C" void kernel_launch(void* const* d_in, const int* in_sizes, int n_in,
                              void* d_out, int out_size, void* d_ws, size_t ws_size,
                              hipStream_t stream) {
  const float* x      = (const float*)d_in[0];
  const float* t      = (const float*)d_in[1];
  const float* n1s    = (const float*)d_in[2];
  const float* n1b    = (const float*)d_in[3];
  const float* n2s    = (const float*)d_in[4];
  const float* n2b    = (const float*)d_in[5];
  const float* tc_w1  = (const float*)d_in[6];
  const float* tc_b1  = (const float*)d_in[7];
  const float* tc_w2  = (const float*)d_in[8];
  const float* tc_b2  = (const float*)d_in[9];
  const float* tc_wa  = (const float*)d_in[10];
  const float* tc_ba  = (const float*)d_in[11];
  const float* tc_wc  = (const float*)d_in[12];
  const float* tc_bc  = (const float*)d_in[13];
  const float* aqk_w  = (const float*)d_in[14];
  const float* av_w   = (const float*)d_in[15];
  const float* aout_w = (const float*)d_in[16];
  const float* doobw  = (const float*)d_in[17];
  const float* cqk_w  = (const float*)d_in[19];
  const float* cv_w   = (const float*)d_in[20];
  const float* cout_w = (const float*)d_in[21];
  const float* tau    = (const float*)d_in[22];
  const float* g1     = (const float*)d_in[23];
  const float* g2     = (const float*)d_in[24];
  float* out = (float*)d_out;

  char* p = (char*)d_ws;
  auto alloc = [&](size_t bytes) -> void* {
    void* r = (void*)p;
    p += (bytes + 255) & ~(size_t)255;
    return r;
  };
  float* emb   = (float*)alloc(2 * 4096 * 4);
  float* partA = (float*)alloc(32 * 2 * 4096 * 4);
  float* partB = (float*)alloc(32 * 2 * 4096 * 4);
  float* h1    = (float*)alloc(2 * 4096 * 4);
  float* h2    = (float*)alloc(2 * 4096 * 4);
  float* avec  = (float*)alloc(2 * 4096 * 4);
  float* cvec  = (float*)alloc(2 * 4096 * 4);
  float* sca   = (float*)alloc(2 * 1024 * 4);
  float* scc   = (float*)alloc(2 * 1024 * 4);
  float* agv   = (float*)alloc(2 * 1024 * 4);
  float* cgv   = (float*)alloc(2 * 1024 * 4);
  float* phi   = (float*)alloc(4096 * 4);
  float* pmax  = (float*)alloc(2 * 4);
  float* q2buf = (float*)alloc(2 * 16 * 2048 * 4);
  float* ebuf  = (float*)alloc(2 * 16 * 2048 * 4);
  float* dotp  = (float*)alloc((size_t)8 * 16 * 16384 * 4);
  bf16* attnc  = (bf16*)alloc(16 * 128 * 128 * 2);
  bf16* wt     = (bf16*)alloc((size_t)6 * 1024 * 1024 * 2);
  bf16* xbf    = (bf16*)alloc((size_t)M_ * 1024 * 2);
  bf16* qkbf   = (bf16*)alloc((size_t)M_ * 1024 * 2);
  bf16* vbuf   = (bf16*)alloc((size_t)M_ * 1024 * 2);
  bf16* wbuf   = (bf16*)alloc((size_t)M_ * 1024 * 2);
  (void)ws_size; (void)in_sizes; (void)n_in; (void)out_size;

  // concatenated (N x K) weights: token [qk; v] (2048x1024), channel [cqk; cv]
  bf16* wt_tok  = wt;                              // 2048 x 1024
  bf16* wt_out  = wt + (size_t)2 * 1048576;        // 1024 x 1024
  bf16* wt_ch   = wt + (size_t)3 * 1048576;        // 2048 x 1024
  bf16* wt_cout = wt + (size_t)5 * 1048576;        // 1024 x 1024

  dim3 blk(256);
  wtconv6_kernel<<<dim3(32, 32, 6), blk, 0, stream>>>(
      aqk_w, av_w, aout_w, cqk_w, cv_w, cout_w,
      wt_tok, wt_tok + (size_t)1048576, wt_out,
      wt_ch,  wt_ch  + (size_t)1048576, wt_cout);

  // --- stage A: time conditioning ---
  emb_kernel<<<32, blk, 0, stream>>>(t, emb);
  gemv_kernel<<<dim3(8, 32), blk, 0, stream>>>(emb, tc_w1, partA);
  gemv_reduce_kernel<<<32, blk, 0, stream>>>(partA, tc_b1, h1, 1);
  gemv_kernel<<<dim3(8, 32), blk, 0, stream>>>(h1, tc_w2, partA);
  gemv_reduce_kernel<<<32, blk, 0, stream>>>(partA, tc_b2, h2, 1);
  gemv_kernel<<<dim3(8, 32), blk, 0, stream>>>(h2, tc_wa, partA);
  gemv_kernel<<<dim3(8, 32), blk, 0, stream>>>(h2, tc_wc, partB);
  gemv_reduce_kernel<<<32, blk, 0, stream>>>(partA, tc_ba, avec, 0);
  gemv_reduce_kernel<<<32, blk, 0, stream>>>(partB, tc_bc, cvec, 0);
  postA_kernel<<<8, blk, 0, stream>>>(avec, cvec, g1, g2, sca, scc, agv, cgv);

  // --- token attention ---
  ln_mod_kernel<<<4096, blk, 0, stream>>>(x, n1s, n1b, avec, doobw, phi, xbf);
  phimax_kernel<<<2, blk, 0, stream>>>(phi, pmax);
  gemm_kernel<10, 128><<<dim3(32, 16), blk, 0, stream>>>(xbf, wt_tok, sca, nullptr, qkbf, vbuf);
  q2e_kernel<<<256, blk, 0, stream>>>(qkbf, phi, pmax, q2buf, ebuf);
  flash_kernel<<<dim3(16, 32), dim3(512), 0, stream>>>(qkbf, vbuf, q2buf, ebuf, wbuf);
  gemm_kernel<4, 64><<<dim3(64, 8), blk, 0, stream>>>(wbuf, wt_out, agv, x, out, nullptr);

  // --- channel attention ---
  ln_mod_kernel<<<4096, blk, 0, stream>>>(out, n2s, n2b, cvec, nullptr, nullptr, xbf);
  gemm_kernel<11, 128><<<dim3(32, 16), blk, 0, stream>>>(xbf, wt_ch, scc, nullptr, qkbf, vbuf);
  gram_kernel<<<dim3(16, 8), blk, 0, stream>>>(qkbf, dotp);
  chsm_kernel<<<2048, dim3(128), 0, stream>>>(dotp, tau, attnc);
  chav_kernel<<<dim3(32, 16), blk, 0, stream>>>(attnc, vbuf, wbuf);
  gemm_kernel<4, 64><<<dim3(64, 8), blk, 0, stream>>>(wbuf, wt_cout, cgv, out, out, nullptr);
}

// Round 3
// 575.472 us; speedup vs baseline: 1.1174x; 1.0019x over previous
//
#include <hip/hip_runtime.h>
#include <hip/hip_bf16.h>
#include <math.h>

typedef __bf16 bf16;
typedef bf16 bf16x8 __attribute__((ext_vector_type(8)));
typedef bf16 bf16x2 __attribute__((ext_vector_type(2)));
typedef float f32x4 __attribute__((ext_vector_type(4)));

#define B_   2
#define N_   2048
#define D_   1024
#define H_   16
#define HC_  8
#define M_   (B_*N_)   // 4096 rows in all big GEMMs

// async global->LDS 16B: lds dest = wave-uniform base + lane*16
__device__ __forceinline__ void gl16(const bf16* g, bf16* lds_base) {
#if __has_builtin(__builtin_amdgcn_global_load_lds)
  __builtin_amdgcn_global_load_lds((const __attribute__((address_space(1))) void*)g,
                                   (__attribute__((address_space(3))) void*)lds_base,
                                   16, 0, 0);
#else
  int lane = threadIdx.x & 63;
  *(uint4*)(lds_base + lane * 8) = *(const uint4*)g;
#endif
}

// packed f32 pair -> bf16x2 (RNE), single instruction
__device__ __forceinline__ bf16x2 cvt_pk_bf16(float lo, float hi) {
  unsigned int r;
  asm("v_cvt_pk_bf16_f32 %0, %1, %2" : "=v"(r) : "v"(lo), "v"(hi));
  union { unsigned int u; bf16x2 v; } c;
  c.u = r;
  return c.v;
}

// ============================================================
// Stage A: time-conditioning MLP (GEMV, B=2 rows)
// ============================================================
__global__ __launch_bounds__(256) void emb_kernel(const float* __restrict__ tin,
                                                  float* __restrict__ emb) {
  int idx = blockIdx.x * 256 + threadIdx.x;   // 0..8191
  int b = idx >> 12, p = idx & 4095;
  float tv = tin[b];
  int half = p & 2047;
  float freq = expf(-logf(10000.f) * (float)half * (1.f / 2048.f));
  float arg = tv * freq;
  emb[idx] = (p < 2048) ? cosf(arg) : sinf(arg);
}

__global__ __launch_bounds__(256) void gemv_kernel(const float* __restrict__ x,
                                                   const float* __restrict__ W,
                                                   float* __restrict__ part) {
  __shared__ float xs[2][128];
  int t = threadIdx.x;
  int j0 = blockIdx.x * 512;
  int k0 = blockIdx.y * 128;
  if (t < 128) xs[0][t] = x[k0 + t];
  else         xs[1][t - 128] = x[4096 + k0 + (t - 128)];
  __syncthreads();
  float a00 = 0.f, a01 = 0.f, a10 = 0.f, a11 = 0.f;
  int j = j0 + t * 2;
  #pragma unroll 8
  for (int k = 0; k < 128; k++) {
    float2 wv = *(const float2*)(W + (size_t)(k0 + k) * 4096 + j);
    float x0 = xs[0][k], x1 = xs[1][k];
    a00 += x0 * wv.x; a01 += x0 * wv.y;
    a10 += x1 * wv.x; a11 += x1 * wv.y;
  }
  *(float2*)(part + (size_t)(blockIdx.y * 2 + 0) * 4096 + j) = make_float2(a00, a01);
  *(float2*)(part + (size_t)(blockIdx.y * 2 + 1) * 4096 + j) = make_float2(a10, a11);
}

__global__ __launch_bounds__(256) void gemv_reduce_kernel(const float* __restrict__ part,
                                                          const float* __restrict__ bias,
                                                          float* __restrict__ y, int act) {
  int idx = blockIdx.x * 256 + threadIdx.x;   // 0..8191
  int b = idx >> 12, j = idx & 4095;
  float s = bias[j];
  #pragma unroll
  for (int kc = 0; kc < 32; kc++) s += part[(size_t)(kc * 2 + b) * 4096 + j];
  if (act) s = s / (1.f + expf(-s));          // silu
  y[idx] = s;
}

__global__ __launch_bounds__(256) void postA_kernel(const float* __restrict__ avec,
                                                    const float* __restrict__ cvec,
                                                    const float* __restrict__ g1,
                                                    const float* __restrict__ g2,
                                                    float* __restrict__ sca, float* __restrict__ scc,
                                                    float* __restrict__ agv, float* __restrict__ cgv) {
  int idx = blockIdx.x * 256 + threadIdx.x;   // 0..2047
  int b = idx >> 10, d = idx & 1023;
  sca[idx] = expf(avec[b * 4096 + 3072 + d]);
  scc[idx] = expf(cvec[b * 4096 + 3072 + d]);
  agv[idx] = avec[b * 4096 + 2048 + d] * g1[d];
  cgv[idx] = cvec[b * 4096 + 2048 + d] * g2[d];
}

// ============================================================
// Weight fp32 (K x N) -> bf16 transposed (N x K), 6 weights in one launch
// ============================================================
__global__ __launch_bounds__(256) void wtconv6_kernel(const float* w0, const float* w1,
                                                      const float* w2, const float* w3,
                                                      const float* w4, const float* w5,
                                                      bf16* o0, bf16* o1, bf16* o2,
                                                      bf16* o3, bf16* o4, bf16* o5) {
  const float* W; bf16* Wt;
  switch (blockIdx.z) {
    case 0: W = w0; Wt = o0; break;
    case 1: W = w1; Wt = o1; break;
    case 2: W = w2; Wt = o2; break;
    case 3: W = w3; Wt = o3; break;
    case 4: W = w4; Wt = o4; break;
    default: W = w5; Wt = o5; break;
  }
  __shared__ float tile[32][33];
  int t = threadIdx.x;
  int i = t >> 5, j = t & 31;
  int n0 = blockIdx.x * 32, k0 = blockIdx.y * 32;
  #pragma unroll
  for (int u = 0; u < 4; u++) {
    int k = i + u * 8;
    tile[k][j] = W[(size_t)(k0 + k) * 1024 + n0 + j];
  }
  __syncthreads();
  #pragma unroll
  for (int u = 0; u < 4; u++) {
    int n = i + u * 8;
    Wt[(size_t)(n0 + n) * 1024 + k0 + j] = (bf16)tile[j][n];
  }
}

// ============================================================
// LayerNorm + modulate -> bf16 (+ optional phi = x1 . doob_w)
// ============================================================
__global__ __launch_bounds__(256) void ln_mod_kernel(const float* __restrict__ xin,
                                                     const float* __restrict__ nsc,
                                                     const float* __restrict__ nbi,
                                                     const float* __restrict__ mod,
                                                     const float* __restrict__ doobw,
                                                     float* __restrict__ phi,
                                                     bf16* __restrict__ outp) {
  int row = blockIdx.x;              // 0..4095
  int b = row >> 11;
  int t = threadIdx.x;
  const float* xr = xin + (size_t)row * 1024;
  float v[4], s = 0.f, ss = 0.f;
  #pragma unroll
  for (int u = 0; u < 4; u++) { v[u] = xr[t + u * 256]; s += v[u]; ss += v[u] * v[u]; }
  #pragma unroll
  for (int off = 1; off < 64; off <<= 1) { s += __shfl_xor(s, off, 64); ss += __shfl_xor(ss, off, 64); }
  __shared__ float sb[4], ssb[4], pb[4];
  if ((t & 63) == 0) { sb[t >> 6] = s; ssb[t >> 6] = ss; }
  __syncthreads();
  s = sb[0] + sb[1] + sb[2] + sb[3];
  ss = ssb[0] + ssb[1] + ssb[2] + ssb[3];
  float mu = s * (1.f / 1024.f);
  float var = ss * (1.f / 1024.f) - mu * mu;
  float rs = rsqrtf(var + 1e-6f);
  const float* shv = mod + b * 4096;
  const float* scv = mod + b * 4096 + 1024;
  float ph = 0.f;
  #pragma unroll
  for (int u = 0; u < 4; u++) {
    int d = t + u * 256;
    float y = (v[u] - mu) * rs * nsc[d] + nbi[d];
    float ym = y * (1.f + scv[d]) + shv[d];
    outp[(size_t)row * 1024 + d] = (bf16)ym;
    if (doobw) ph += ym * doobw[d];
  }
  if (doobw) {
    #pragma unroll
    for (int off = 1; off < 64; off <<= 1) ph += __shfl_xor(ph, off, 64);
    if ((t & 63) == 0) pb[t >> 6] = ph;
    __syncthreads();
    if (t == 0) phi[row] = pb[0] + pb[1] + pb[2] + pb[3];
  }
}

__global__ __launch_bounds__(256) void phimax_kernel(const float* __restrict__ phi,
                                                     float* __restrict__ pm) {
  int b = blockIdx.x;
  int t = threadIdx.x;
  float m = -1e30f;
  #pragma unroll
  for (int u = 0; u < 8; u++) m = fmaxf(m, phi[b * 2048 + t + u * 256]);
  #pragma unroll
  for (int off = 1; off < 64; off <<= 1) m = fmaxf(m, __shfl_xor(m, off, 64));
  __shared__ float mb[4];
  if ((t & 63) == 0) mb[t >> 6] = m;
  __syncthreads();
  if (t == 0) pm[b] = fmaxf(fmaxf(mb[0], mb[1]), fmaxf(mb[2], mb[3]));
}

// ============================================================
// bf16 MFMA GEMM w/ global_load_lds staging, XOR-swizzled LDS (stride 64, no pad)
// TM in {64,128}, N-tile = 128. 2x2 waves.
// MODE 10: token fused out: col<1024 -> qkh = val*sca, head-major (B,H,N,64);
//          col>=1024 -> vtb chunk-blocked (B,H,32nc,64dh,64n)   [contiguous
//          8KB K/V chunks for flash DRAM/L2 locality]
// MODE 11: channel fused:   col<1024 -> qkct = val*scc (B,HC,128,N); col>=1024 -> v (B,N,D)
// MODE 4 : out = resid + val*gate (fp32, B,N,D)
// ============================================================
template <int MODE, int TM>
__global__ __launch_bounds__(256) void gemm_kernel(const bf16* __restrict__ A,
                                                   const bf16* __restrict__ Wt,
                                                   const float* __restrict__ scale,
                                                   const float* __restrict__ resid,
                                                   void* __restrict__ out0,
                                                   void* __restrict__ out1) {
  constexpr int K = 1024;
  constexpr int WM = TM / 2;       // wave rows
  constexpr int IT = WM / 16;      // i tiles per wave
  __shared__ bf16 As[TM * 64];
  __shared__ bf16 Bs[128 * 64];
  const int m0 = blockIdx.x * TM;
  const int n0 = blockIdx.y * 128;
  const int t = threadIdx.x, lane = t & 63, wid = t >> 6;
  const int wy = wid >> 1, wx = wid & 1;
  const int ml = lane & 15, quad = lane >> 4, rq = quad * 4, kq = quad * 8;
  // staging: lane -> (row srow, swizzled source chunk)
  const int srow = lane >> 3;
  const int schunk = (lane & 7) ^ srow;
  const bf16* gA = A  + (size_t)(m0 + wid * (TM / 4) + srow) * K + schunk * 8;
  const bf16* gB = Wt + (size_t)(n0 + wid * 32 + srow) * K + schunk * 8;
  bf16* lA = As + (wid * (TM / 4)) * 64;
  bf16* lB = Bs + (wid * 32) * 64;
  const int mlm = ml & 7;

  f32x4 acc[IT][4] = {};
  for (int k0 = 0; k0 < K; k0 += 64) {
    __syncthreads();
    #pragma unroll
    for (int q = 0; q < TM / 32; q++)
      gl16(gA + (size_t)q * 8 * K + k0, lA + q * 8 * 64);
    #pragma unroll
    for (int q = 0; q < 4; q++)
      gl16(gB + (size_t)q * 8 * K + k0, lB + q * 8 * 64);
    __syncthreads();
    #pragma unroll
    for (int ks = 0; ks < 2; ks++) {
      const int slot = ((ks * 4 + quad) ^ mlm) * 8;
      bf16x8 af[IT], bfv[4];
      #pragma unroll
      for (int i = 0; i < IT; i++)
        af[i] = *(const bf16x8*)(As + (wy * WM + i * 16 + ml) * 64 + slot);
      #pragma unroll
      for (int j = 0; j < 4; j++)
        bfv[j] = *(const bf16x8*)(Bs + (wx * 64 + j * 16 + ml) * 64 + slot);
      #pragma unroll
      for (int i = 0; i < IT; i++)
        #pragma unroll
        for (int j = 0; j < 4; j++)
          acc[i][j] = __builtin_amdgcn_mfma_f32_16x16x32_bf16(af[i], bfv[j], acc[i][j], 0, 0, 0);
    }
  }
  // epilogue
  #pragma unroll
  for (int i = 0; i < IT; i++) {
    #pragma unroll
    for (int j = 0; j < 4; j++) {
      int col = n0 + wx * 64 + j * 16 + ml;
      #pragma unroll
      for (int r = 0; r < 4; r++) {
        int row = m0 + wy * WM + i * 16 + rq + r;
        int b = row >> 11, n = row & 2047;
        float val = acc[i][j][r];
        if constexpr (MODE == 10) {
          if (col < 1024) {
            int h = col >> 6, dh = col & 63;
            ((bf16*)out0)[((size_t)(b * 16 + h) * 2048 + n) * 64 + dh] =
                (bf16)(val * scale[b * 1024 + col]);
          } else {
            int c2 = col - 1024;
            int h = c2 >> 6, dh = c2 & 63;
            ((bf16*)out1)[(((size_t)(b * 16 + h) * 32 + (n >> 6)) * 64 + dh) * 64 + (n & 63)] =
                (bf16)val;
          }
        } else if constexpr (MODE == 11) {
          if (col < 1024) {
            float sv = val * scale[b * 1024 + col];
            ((bf16*)out0)[((size_t)((b * 8 + (col >> 7)) * 128 + (col & 127))) * 2048 + n] = (bf16)sv;
          } else {
            ((bf16*)out1)[(size_t)row * 1024 + (col - 1024)] = (bf16)val;
          }
        } else {
          float g = scale[b * 1024 + col];
          ((float*)out0)[(size_t)row * 1024 + col] =
              resid[(size_t)row * 1024 + col] + val * g;
        }
      }
    }
  }
}

// ============================================================
// q2 per (b,h,n) + e = (phi - q2 - phimax[b]) -- both pre-scaled by log2(e)
// head-major qkh input: one thread per (bh,n) row, 64 contiguous bf16.
// ============================================================
__global__ __launch_bounds__(256) void q2e_kernel(const bf16* __restrict__ qkh,
                                                  const float* __restrict__ phi,
                                                  const float* __restrict__ pm,
                                                  float* __restrict__ q2buf,
                                                  float* __restrict__ ebuf) {
  int idx = blockIdx.x * 256 + threadIdx.x;   // 0..65535 = bh*2048 + n
  int bh = idx >> 11, n = idx & 2047;
  int b = bh >> 4;
  const bf16* qr = qkh + (size_t)idx * 64;
  float q = 0.f;
  #pragma unroll
  for (int u = 0; u < 8; u++) {
    bf16x8 v = *(const bf16x8*)(qr + u * 8);
    #pragma unroll
    for (int e = 0; e < 8; e++) { float f = (float)v[e]; q += f * f; }
  }
  q2buf[idx] = q * 1.44269504f;
  ebuf[idx]  = (phi[b * 2048 + n] - q - pm[b]) * 1.44269504f;
}

// ============================================================
// Flash attention, static-max softmax, swapped-operand QK^T.
// Linear grid 1024, XCD-swizzled: bh = (bid&7)*4 + ((bid>>3)>>5), mt=(bid>>3)&31.
// All 32 m-tile blocks of a bh land on ONE XCD -> its 512KB K/V stays L2-resident
// (4 bh x 512KB = 2MB per 4MB XCD-L2). 256 thr = 4 waves, 64 Q-rows/block,
// 40KB LDS -> 4 blocks/CU (4 independent barrier groups cover residual latency).
// S^T = mfma(K,Q) puts a full P row lane-local (q = ml): pack to bf16 with
// v_cvt_pk, 8 dword stores into a wave-private swizzled P strip, b128 reload
// as the PV A-fragment. K/V double-buffered via global_load_lds with
// pre-swizzled source (involution c ^= r&7); one barrier per kv-chunk.
// ============================================================
__global__ __launch_bounds__(256, 4) void flash_kernel(const bf16* __restrict__ qkh,  // (B,H,N,64)
                                                       const bf16* __restrict__ vtb,  // (B,H,32,64,64)
                                                       const float* __restrict__ q2buf,
                                                       const float* __restrict__ ebuf,
                                                       bf16* __restrict__ wout) {     // (B,N,D)
  int bid = blockIdx.x;
  int ii = bid >> 3;
  int bh = (bid & 7) * 4 + (ii >> 5);   // 4 bh per XCD
  int mt = ii & 31;
  int b = bh >> 4, h = bh & 15;
  int m0 = mt * 64;
  int t = threadIdx.x, lane = t & 63, w = t >> 6;     // 4 waves
  int ml = lane & 15, quad = lane >> 4;
  int mlm = ml & 7, q1 = quad & 1, qh = quad >> 1;

  __shared__ __align__(16) bf16 Ks[2][64 * 64];
  __shared__ __align__(16) bf16 Vs[2][64 * 64];
  __shared__ __align__(16) bf16 Ps[4 * 16 * 64];      // per-wave 16x64 P strip

  // staging: thread owns 2x16B K chunks + 2x16B V chunks per kv-tile (4 gl16).
  // LDS dest is linear (gl16: wave base + lane*16); source chunk pre-swizzled.
  int sr = lane >> 3, swz = (lane & 7) ^ sr;
  const bf16* gK = qkh + ((size_t)bh * 2048 + w * 16 + sr) * 64 + swz * 8;
  const bf16* gV = vtb + (size_t)bh * 131072 + (w * 16 + sr) * 64 + swz * 8;

  // Q fragments in registers (loop-invariant); B-operand row = q = w*16+ml
  const bf16* qrow = qkh + ((size_t)bh * 2048 + m0 + w * 16 + ml) * 64;
  bf16x8 qf0 = *(const bf16x8*)(qrow + quad * 8);
  bf16x8 qf1 = *(const bf16x8*)(qrow + 32 + quad * 8);

  float q2l = q2buf[(size_t)bh * 2048 + m0 + w * 16 + ml];   // pre-scaled log2e
  const float* ep = ebuf + (size_t)bh * 2048;                // pre-scaled log2e

  bf16* Pb = Ps + (w * 16 + ml) * 64;   // this lane's P row (q = w*16+ml)
  f32x4 oacc[4] = {};
  float rs = 0.f;

  // prologue stage chunk 0 -> buf 0
  gl16(gK,       &Ks[0][w * 1024]);
  gl16(gK + 512, &Ks[0][w * 1024 + 512]);
  gl16(gV,       &Vs[0][w * 1024]);
  gl16(gV + 512, &Vs[0][w * 1024 + 512]);

  #pragma unroll 2
  for (int nc = 0; nc < 32; nc++) {
    int cur = nc & 1;
    __syncthreads();                     // drains cur's stage (vmcnt 0) + barrier
    if (nc + 1 < 32) {                   // next chunk flies across this compute
      const bf16* nk = gK + (size_t)(nc + 1) * 4096;
      const bf16* nv = gV + (size_t)(nc + 1) * 4096;
      bf16* dk = &Ks[cur ^ 1][w * 1024];
      bf16* dv = &Vs[cur ^ 1][w * 1024];
      gl16(nk,       dk);
      gl16(nk + 512, dk + 512);
      gl16(nv,       dv);
      gl16(nv + 512, dv + 512);
    }
    const bf16* Kc = Ks[cur];
    const bf16* Vc = Vs[cur];

    // S^T = K.Q^T : output row = kv-local (quad*4+r+16j), col = q (= ml)
    f32x4 sacc[4] = {};
    __builtin_amdgcn_s_setprio(1);
    #pragma unroll
    for (int ks = 0; ks < 2; ks++) {
      bf16x8 qb = ks ? qf1 : qf0;
      #pragma unroll
      for (int j = 0; j < 4; j++) {
        bf16x8 ka = *(const bf16x8*)(Kc + (j * 16 + ml) * 64 + ((4 * ks + quad) ^ mlm) * 8);
        sacc[j] = __builtin_amdgcn_mfma_f32_16x16x32_bf16(ka, qb, sacc[j], 0, 0, 0);
      }
    }
    __builtin_amdgcn_s_setprio(0);

    // softmax: lane holds P[q=ml][kv = 16j + 4quad + r]; pack pairs, store
    // dwords into the swizzled strip (chunk ^= row&7 — same involution as reads)
    const float* epc = ep + nc * 64;
    #pragma unroll
    for (int j = 0; j < 4; j++) {
      float4 ev = *(const float4*)(epc + j * 16 + quad * 4);
      float p0 = exp2f(fmaf(2.88539008f, sacc[j][0], ev.x - q2l));
      float p1 = exp2f(fmaf(2.88539008f, sacc[j][1], ev.y - q2l));
      float p2 = exp2f(fmaf(2.88539008f, sacc[j][2], ev.z - q2l));
      float p3 = exp2f(fmaf(2.88539008f, sacc[j][3], ev.w - q2l));
      rs += (p0 + p1) + (p2 + p3);
      int sl = (((2 * j + qh) ^ mlm) * 4 + 2 * q1) * 2;    // bf16 idx of dword slot
      *(bf16x2*)(Pb + sl)     = cvt_pk_bf16(p0, p1);
      *(bf16x2*)(Pb + sl + 2) = cvt_pk_bf16(p2, p3);
    }
    // wave-private strip: in-wave DS ordering suffices; fence compiler reorder
    __builtin_amdgcn_sched_barrier(0);

    __builtin_amdgcn_s_setprio(1);
    #pragma unroll
    for (int ks = 0; ks < 2; ks++) {
      bf16x8 pa = *(const bf16x8*)(Pb + ((4 * ks + quad) ^ mlm) * 8);
      #pragma unroll
      for (int jd = 0; jd < 4; jd++) {
        bf16x8 vb = *(const bf16x8*)(Vc + (jd * 16 + ml) * 64 + ((4 * ks + quad) ^ mlm) * 8);
        oacc[jd] = __builtin_amdgcn_mfma_f32_16x16x32_bf16(pa, vb, oacc[jd], 0, 0, 0);
      }
    }
    __builtin_amdgcn_s_setprio(0);
  }

  // row-sum: lane has partial for q = w*16+ml over its kv subset; fold quads
  rs += __shfl_xor(rs, 16, 64);
  rs += __shfl_xor(rs, 32, 64);
  float rinv = 1.f / rs;

  int rq = quad * 4;
  float rv[4];
  #pragma unroll
  for (int r = 0; r < 4; r++) rv[r] = __shfl(rinv, rq + r, 64);

  bf16* wrow = wout + (size_t)(b * 2048 + m0 + w * 16) * 1024 + h * 64;
  #pragma unroll
  for (int jd = 0; jd < 4; jd++)
    #pragma unroll
    for (int r = 0; r < 4; r++)
      wrow[(size_t)(rq + r) * 1024 + jd * 16 + ml] = (bf16)(oacc[jd][r] * rv[r]);
}

// ============================================================
// Channel attention
// ============================================================
// split-K Gram: grid (16 bh, 8 kslice): dotp[(ks*16+bh)][c][d] over 256-deep slice
__global__ __launch_bounds__(256) void gram_kernel(const bf16* __restrict__ qkct,
                                                   float* __restrict__ dotp) {
  int bh = blockIdx.x, ksl = blockIdx.y;
  const bf16* Q = qkct + (size_t)bh * 128 * 2048 + ksl * 256;
  __shared__ bf16 Ts[128 * 40];
  int t = threadIdx.x, lane = t & 63, w = t >> 6;
  int ml = lane & 15, kq = (lane >> 4) * 8, rq = (lane >> 4) * 4;
  f32x4 acc[2][8] = {};
  for (int k0 = 0; k0 < 256; k0 += 32) {
    __syncthreads();
    #pragma unroll
    for (int u = 0; u < 2; u++) {
      int idx = u * 256 + t;                 // 512 units: 128 rows x 4 x 16B
      int r = idx >> 2, seg = (idx & 3) * 8;
      *(uint4*)(Ts + r * 40 + seg) = *(const uint4*)(Q + (size_t)r * 2048 + k0 + seg);
    }
    __syncthreads();
    bf16x8 afr[2], bfr[8];
    #pragma unroll
    for (int i = 0; i < 2; i++) afr[i] = *(const bf16x8*)(Ts + (w * 32 + i * 16 + ml) * 40 + kq);
    #pragma unroll
    for (int j = 0; j < 8; j++) bfr[j] = *(const bf16x8*)(Ts + (j * 16 + ml) * 40 + kq);
    #pragma unroll
    for (int i = 0; i < 2; i++)
      #pragma unroll
      for (int j = 0; j < 8; j++)
        acc[i][j] = __builtin_amdgcn_mfma_f32_16x16x32_bf16(afr[i], bfr[j], acc[i][j], 0, 0, 0);
  }
  float* outp = dotp + ((size_t)ksl * 16 + bh) * 16384;
  #pragma unroll
  for (int i = 0; i < 2; i++)
    #pragma unroll
    for (int j = 0; j < 8; j++)
      #pragma unroll
      for (int r = 0; r < 4; r++) {
        int c = w * 32 + i * 16 + rq + r, d = j * 16 + ml;
        outp[c * 128 + d] = acc[i][j][r];
      }
}

// softmax over d, folding the 8-way partial sum. grid 2048 (bh*128+c), 128 thr.
__global__ __launch_bounds__(128) void chsm_kernel(const float* __restrict__ dotp,
                                                   const float* __restrict__ tau,
                                                   bf16* __restrict__ attnc) {
  int blk = blockIdx.x;
  int bh = blk >> 7, c = blk & 127, hc = bh & 7;
  int d = threadIdx.x;
  float dot = 0.f, dd = 0.f;
  #pragma unroll
  for (int kc = 0; kc < 8; kc++) {
    const float* pp = dotp + ((size_t)kc * 16 + bh) * 16384;
    dot += pp[c * 128 + d];
    dd  += pp[d * 128 + d];
  }
  __shared__ float diag[128];
  __shared__ float red[2], red2[2];
  diag[d] = dd;
  __syncthreads();
  float qc = diag[c];
  float sc = tau[hc] * rsqrtf(2048.f);
  float lg = sc * (2.f * dot - qc - dd);
  float mx = lg;
  #pragma unroll
  for (int off = 1; off < 64; off <<= 1) mx = fmaxf(mx, __shfl_xor(mx, off, 64));
  if ((d & 63) == 0) red[d >> 6] = mx;
  __syncthreads();
  mx = fmaxf(red[0], red[1]);
  float e = exp2f((lg - mx) * 1.44269504f);
  float sm = e;
  #pragma unroll
  for (int off = 1; off < 64; off <<= 1) sm += __shfl_xor(sm, off, 64);
  if ((d & 63) == 0) red2[d >> 6] = sm;
  __syncthreads();
  sm = red2[0] + red2[1];
  attnc[(size_t)bh * 16384 + c * 128 + d] = (bf16)(e / sm);
}

// wc[c][n] = sum_d attnc[c][d] * vc[b][n][hc*128+d]; write wcn (B,N,D)
__global__ __launch_bounds__(256) void chav_kernel(const bf16* __restrict__ attnc,
                                                   const bf16* __restrict__ vc,
                                                   bf16* __restrict__ wcn) {
  int nb = blockIdx.x, bh = blockIdx.y;
  int b = bh >> 3, hc = bh & 7;
  int n0 = nb * 64;
  __shared__ bf16 As[128 * 136];
  __shared__ bf16 Bs[64 * 136];
  int t = threadIdx.x, lane = t & 63, w = t >> 6;
  int ml = lane & 15, kq = (lane >> 4) * 8, rq = (lane >> 4) * 4;
  #pragma unroll
  for (int u = 0; u < 8; u++) {                  // A: 128 rows x 16 x 16B
    int idx = u * 256 + t;
    int r = idx >> 4, seg = (idx & 15) * 8;
    *(uint4*)(As + r * 136 + seg) = *(const uint4*)(attnc + (size_t)bh * 16384 + r * 128 + seg);
  }
  #pragma unroll
  for (int u = 0; u < 4; u++) {                  // B: 64 rows x 16 x 16B
    int idx = u * 256 + t;
    int r = idx >> 4, seg = (idx & 15) * 8;
    *(uint4*)(Bs + r * 136 + seg) =
        *(const uint4*)(vc + (size_t)(b * 2048 + n0 + r) * 1024 + hc * 128 + seg);
  }
  __syncthreads();
  f32x4 acc[2][4] = {};
  #pragma unroll
  for (int ks = 0; ks < 4; ks++) {
    bf16x8 afr[2], bfr[4];
    #pragma unroll
    for (int i = 0; i < 2; i++)
      afr[i] = *(const bf16x8*)(As + (w * 32 + i * 16 + ml) * 136 + ks * 32 + kq);
    #pragma unroll
    for (int j = 0; j < 4; j++)
      bfr[j] = *(const bf16x8*)(Bs + (j * 16 + ml) * 136 + ks * 32 + kq);
    #pragma unroll
    for (int i = 0; i < 2; i++)
      #pragma unroll
      for (int j = 0; j < 4; j++)
        acc[i][j] = __builtin_amdgcn_mfma_f32_16x16x32_bf16(afr[i], bfr[j], acc[i][j], 0, 0, 0);
  }
  #pragma unroll
  for (int i = 0; i < 2; i++)
    #pragma unroll
    for (int j = 0; j < 4; j++)
      #pragma unroll
      for (int r = 0; r < 4; r++) {
        int c = w * 32 + i * 16 + rq + r;
        int n = n0 + j * 16 + ml;
        wcn[(size_t)(b * 2048 + n) * 1024 + hc * 128 + c] = (bf16)acc[i][j][r];
      }
}

// ============================================================
// Host launcher
// ============================================================
extern "C" void kernel_launch(void* const* d_in, const int* in_sizes, int n_in,
                              void* d_out, int out_size, void* d_ws, size_t ws_size,
                              hipStream_t stream) {
  const float* x      = (const float*)d_in[0];
  const float* t      = (const float*)d_in[1];
  const float* n1s    = (const float*)d_in[2];
  const float* n1b    = (const float*)d_in[3];
  const float* n2s    = (const float*)d_in[4];
  const float* n2b    = (const float*)d_in[5];
  const float* tc_w1  = (const float*)d_in[6];
  const float* tc_b1  = (const float*)d_in[7];
  const float* tc_w2  = (const float*)d_in[8];
  const float* tc_b2  = (const float*)d_in[9];
  const float* tc_wa  = (const float*)d_in[10];
  const float* tc_ba  = (const float*)d_in[11];
  const float* tc_wc  = (const float*)d_in[12];
  const float* tc_bc  = (const float*)d_in[13];
  const float* aqk_w  = (const float*)d_in[14];
  const float* av_w   = (const float*)d_in[15];
  const float* aout_w = (const float*)d_in[16];
  const float* doobw  = (const float*)d_in[17];
  const float* cqk_w  = (const float*)d_in[19];
  const float* cv_w   = (const float*)d_in[20];
  const float* cout_w = (const float*)d_in[21];
  const float* tau    = (const float*)d_in[22];
  const float* g1     = (const float*)d_in[23];
  const float* g2     = (const float*)d_in[24];
  float* out = (float*)d_out;

  char* p = (char*)d_ws;
  auto alloc = [&](size_t bytes) -> void* {
    void* r = (void*)p;
    p += (bytes + 255) & ~(size_t)255;
    return r;
  };
  float* emb   = (float*)alloc(2 * 4096 * 4);
  float* partA = (float*)alloc(32 * 2 * 4096 * 4);
  float* partB = (float*)alloc(32 * 2 * 4096 * 4);
  float* h1    = (float*)alloc(2 * 4096 * 4);
  float* h2    = (float*)alloc(2 * 4096 * 4);
  float* avec  = (float*)alloc(2 * 4096 * 4);
  float* cvec  = (float*)alloc(2 * 4096 * 4);
  float* sca   = (float*)alloc(2 * 1024 * 4);
  float* scc   = (float*)alloc(2 * 1024 * 4);
  float* agv   = (float*)alloc(2 * 1024 * 4);
  float* cgv   = (float*)alloc(2 * 1024 * 4);
  float* phi   = (float*)alloc(4096 * 4);
  float* pmax  = (float*)alloc(2 * 4);
  float* q2buf = (float*)alloc(2 * 16 * 2048 * 4);
  float* ebuf  = (float*)alloc(2 * 16 * 2048 * 4);
  float* dotp  = (float*)alloc((size_t)8 * 16 * 16384 * 4);
  bf16* attnc  = (bf16*)alloc(16 * 128 * 128 * 2);
  bf16* wt     = (bf16*)alloc((size_t)6 * 1024 * 1024 * 2);
  bf16* xbf    = (bf16*)alloc((size_t)M_ * 1024 * 2);
  bf16* qkbf   = (bf16*)alloc((size_t)M_ * 1024 * 2);
  bf16* vbuf   = (bf16*)alloc((size_t)M_ * 1024 * 2);
  bf16* wbuf   = (bf16*)alloc((size_t)M_ * 1024 * 2);
  (void)ws_size; (void)in_sizes; (void)n_in; (void)out_size;

  // concatenated (N x K) weights: token [qk; v] (2048x1024), channel [cqk; cv]
  bf16* wt_tok  = wt;                              // 2048 x 1024
  bf16* wt_out  = wt + (size_t)2 * 1048576;        // 1024 x 1024
  bf16* wt_ch   = wt + (size_t)3 * 1048576;        // 2048 x 1024
  bf16* wt_cout = wt + (size_t)5 * 1048576;        // 1024 x 1024

  dim3 blk(256);
  wtconv6_kernel<<<dim3(32, 32, 6), blk, 0, stream>>>(
      aqk_w, av_w, aout_w, cqk_w, cv_w, cout_w,
      wt_tok, wt_tok + (size_t)1048576, wt_out,
      wt_ch,  wt_ch  + (size_t)1048576, wt_cout);

  // --- stage A: time conditioning ---
  emb_kernel<<<32, blk, 0, stream>>>(t, emb);
  gemv_kernel<<<dim3(8, 32), blk, 0, stream>>>(emb, tc_w1, partA);
  gemv_reduce_kernel<<<32, blk, 0, stream>>>(partA, tc_b1, h1, 1);
  gemv_kernel<<<dim3(8, 32), blk, 0, stream>>>(h1, tc_w2, partA);
  gemv_reduce_kernel<<<32, blk, 0, stream>>>(partA, tc_b2, h2, 1);
  gemv_kernel<<<dim3(8, 32), blk, 0, stream>>>(h2, tc_wa, partA);
  gemv_kernel<<<dim3(8, 32), blk, 0, stream>>>(h2, tc_wc, partB);
  gemv_reduce_kernel<<<32, blk, 0, stream>>>(partA, tc_ba, avec, 0);
  gemv_reduce_kernel<<<32, blk, 0, stream>>>(partB, tc_bc, cvec, 0);
  postA_kernel<<<8, blk, 0, stream>>>(avec, cvec, g1, g2, sca, scc, agv, cgv);

  // --- token attention ---
  ln_mod_kernel<<<4096, blk, 0, stream>>>(x, n1s, n1b, avec, doobw, phi, xbf);
  phimax_kernel<<<2, blk, 0, stream>>>(phi, pmax);
  gemm_kernel<10, 128><<<dim3(32, 16), blk, 0, stream>>>(xbf, wt_tok, sca, nullptr, qkbf, vbuf);
  q2e_kernel<<<256, blk, 0, stream>>>(qkbf, phi, pmax, q2buf, ebuf);
  flash_kernel<<<dim3(1024), dim3(256), 0, stream>>>(qkbf, vbuf, q2buf, ebuf, wbuf);
  gemm_kernel<4, 64><<<dim3(64, 8), blk, 0, stream>>>(wbuf, wt_out, agv, x, out, nullptr);

  // --- channel attention ---
  ln_mod_kernel<<<4096, blk, 0, stream>>>(out, n2s, n2b, cvec, nullptr, nullptr, xbf);
  gemm_kernel<11, 128><<<dim3(32, 16), blk, 0, stream>>>(xbf, wt_ch, scc, nullptr, qkbf, vbuf);
  gram_kernel<<<dim3(16, 8), blk, 0, stream>>>(qkbf, dotp);
  chsm_kernel<<<2048, dim3(128), 0, stream>>>(dotp, tau, attnc);
  chav_kernel<<<dim3(32, 16), blk, 0, stream>>>(attnc, vbuf, wbuf);
  gemm_kernel<4, 64><<<dim3(64, 8), blk, 0, stream>>>(wbuf, wt_cout, cgv, out, out, nullptr);
}

// Round 5
// 544.199 us; speedup vs baseline: 1.1817x; 1.0575x over previous
//
#include <hip/hip_runtime.h>
#include <hip/hip_bf16.h>
#include <math.h>

typedef __bf16 bf16;
typedef bf16 bf16x8 __attribute__((ext_vector_type(8)));
typedef bf16 bf16x4 __attribute__((ext_vector_type(4)));
typedef bf16 bf16x2 __attribute__((ext_vector_type(2)));
typedef float f32x4 __attribute__((ext_vector_type(4)));

#define B_   2
#define N_   2048
#define D_   1024
#define H_   16
#define HC_  8
#define M_   (B_*N_)   // 4096 rows in all big GEMMs

// async global->LDS 16B: lds dest = wave-uniform base + lane*16
__device__ __forceinline__ void gl16(const bf16* g, bf16* lds_base) {
#if __has_builtin(__builtin_amdgcn_global_load_lds)
  __builtin_amdgcn_global_load_lds((const __attribute__((address_space(1))) void*)g,
                                   (__attribute__((address_space(3))) void*)lds_base,
                                   16, 0, 0);
#else
  int lane = threadIdx.x & 63;
  *(uint4*)(lds_base + lane * 8) = *(const uint4*)g;
#endif
}

// async global->LDS 4B: lds dest = base + lane*4 (per-lane global source)
__device__ __forceinline__ void gl4(const float* g, float* lds_base) {
#if __has_builtin(__builtin_amdgcn_global_load_lds)
  __builtin_amdgcn_global_load_lds((const __attribute__((address_space(1))) void*)g,
                                   (__attribute__((address_space(3))) void*)lds_base,
                                   4, 0, 0);
#else
  int lane = threadIdx.x & 63;
  lds_base[lane] = *g;
#endif
}

// packed f32 pair -> bf16x2 (RNE), single instruction
__device__ __forceinline__ bf16x2 cvt_pk_bf16(float lo, float hi) {
  unsigned int r;
  asm("v_cvt_pk_bf16_f32 %0, %1, %2" : "=v"(r) : "v"(lo), "v"(hi));
  union { unsigned int u; bf16x2 v; } c;
  c.u = r;
  return c.v;
}

// V-column bit-permutation: kv=[eh|ks|quad|el] -> c=[ks|quad|eh|el] (low 2 bits fixed)
__device__ __forceinline__ int vperm(int kv) {
  return (((kv >> 4) & 1) << 5) | (((kv >> 2) & 3) << 3) | (((kv >> 5) & 1) << 2) | (kv & 3);
}

// ============================================================
// Stage A: time-conditioning MLP (GEMV, B=2 rows)
// ============================================================
__global__ __launch_bounds__(256) void emb_kernel(const float* __restrict__ tin,
                                                  float* __restrict__ emb) {
  int idx = blockIdx.x * 256 + threadIdx.x;   // 0..8191
  int b = idx >> 12, p = idx & 4095;
  float tv = tin[b];
  int half = p & 2047;
  float freq = expf(-logf(10000.f) * (float)half * (1.f / 2048.f));
  float arg = tv * freq;
  emb[idx] = (p < 2048) ? cosf(arg) : sinf(arg);
}

__global__ __launch_bounds__(256) void gemv_kernel(const float* __restrict__ x,
                                                   const float* __restrict__ W,
                                                   float* __restrict__ part) {
  __shared__ float xs[2][128];
  int t = threadIdx.x;
  int j0 = blockIdx.x * 512;
  int k0 = blockIdx.y * 128;
  if (t < 128) xs[0][t] = x[k0 + t];
  else         xs[1][t - 128] = x[4096 + k0 + (t - 128)];
  __syncthreads();
  float a00 = 0.f, a01 = 0.f, a10 = 0.f, a11 = 0.f;
  int j = j0 + t * 2;
  #pragma unroll 8
  for (int k = 0; k < 128; k++) {
    float2 wv = *(const float2*)(W + (size_t)(k0 + k) * 4096 + j);
    float x0 = xs[0][k], x1 = xs[1][k];
    a00 += x0 * wv.x; a01 += x0 * wv.y;
    a10 += x1 * wv.x; a11 += x1 * wv.y;
  }
  *(float2*)(part + (size_t)(blockIdx.y * 2 + 0) * 4096 + j) = make_float2(a00, a01);
  *(float2*)(part + (size_t)(blockIdx.y * 2 + 1) * 4096 + j) = make_float2(a10, a11);
}

__global__ __launch_bounds__(256) void gemv_reduce_kernel(const float* __restrict__ part,
                                                          const float* __restrict__ bias,
                                                          float* __restrict__ y, int act) {
  int idx = blockIdx.x * 256 + threadIdx.x;   // 0..8191
  int b = idx >> 12, j = idx & 4095;
  float s = bias[j];
  #pragma unroll
  for (int kc = 0; kc < 32; kc++) s += part[(size_t)(kc * 2 + b) * 4096 + j];
  if (act) s = s / (1.f + expf(-s));          // silu
  y[idx] = s;
}

__global__ __launch_bounds__(256) void postA_kernel(const float* __restrict__ avec,
                                                    const float* __restrict__ cvec,
                                                    const float* __restrict__ g1,
                                                    const float* __restrict__ g2,
                                                    float* __restrict__ sca, float* __restrict__ scc,
                                                    float* __restrict__ agv, float* __restrict__ cgv) {
  int idx = blockIdx.x * 256 + threadIdx.x;   // 0..2047
  int b = idx >> 10, d = idx & 1023;
  sca[idx] = expf(avec[b * 4096 + 3072 + d]);
  scc[idx] = expf(cvec[b * 4096 + 3072 + d]);
  agv[idx] = avec[b * 4096 + 2048 + d] * g1[d];
  cgv[idx] = cvec[b * 4096 + 2048 + d] * g2[d];
}

// ============================================================
// Weight fp32 (K x N) -> bf16 transposed (N x K), 6 weights in one launch
// ============================================================
__global__ __launch_bounds__(256) void wtconv6_kernel(const float* w0, const float* w1,
                                                      const float* w2, const float* w3,
                                                      const float* w4, const float* w5,
                                                      bf16* o0, bf16* o1, bf16* o2,
                                                      bf16* o3, bf16* o4, bf16* o5) {
  const float* W; bf16* Wt;
  switch (blockIdx.z) {
    case 0: W = w0; Wt = o0; break;
    case 1: W = w1; Wt = o1; break;
    case 2: W = w2; Wt = o2; break;
    case 3: W = w3; Wt = o3; break;
    case 4: W = w4; Wt = o4; break;
    default: W = w5; Wt = o5; break;
  }
  __shared__ float tile[32][33];
  int t = threadIdx.x;
  int i = t >> 5, j = t & 31;
  int n0 = blockIdx.x * 32, k0 = blockIdx.y * 32;
  #pragma unroll
  for (int u = 0; u < 4; u++) {
    int k = i + u * 8;
    tile[k][j] = W[(size_t)(k0 + k) * 1024 + n0 + j];
  }
  __syncthreads();
  #pragma unroll
  for (int u = 0; u < 4; u++) {
    int n = i + u * 8;
    Wt[(size_t)(n0 + n) * 1024 + k0 + j] = (bf16)tile[j][n];
  }
}

// ============================================================
// LayerNorm + modulate -> bf16 (+ optional phi = x1 . doob_w)
// ============================================================
__global__ __launch_bounds__(256) void ln_mod_kernel(const float* __restrict__ xin,
                                                     const float* __restrict__ nsc,
                                                     const float* __restrict__ nbi,
                                                     const float* __restrict__ mod,
                                                     const float* __restrict__ doobw,
                                                     float* __restrict__ phi,
                                                     bf16* __restrict__ outp) {
  int row = blockIdx.x;              // 0..4095
  int b = row >> 11;
  int t = threadIdx.x;
  const float* xr = xin + (size_t)row * 1024;
  float v[4], s = 0.f, ss = 0.f;
  #pragma unroll
  for (int u = 0; u < 4; u++) { v[u] = xr[t + u * 256]; s += v[u]; ss += v[u] * v[u]; }
  #pragma unroll
  for (int off = 1; off < 64; off <<= 1) { s += __shfl_xor(s, off, 64); ss += __shfl_xor(ss, off, 64); }
  __shared__ float sb[4], ssb[4], pb[4];
  if ((t & 63) == 0) { sb[t >> 6] = s; ssb[t >> 6] = ss; }
  __syncthreads();
  s = sb[0] + sb[1] + sb[2] + sb[3];
  ss = ssb[0] + ssb[1] + ssb[2] + ssb[3];
  float mu = s * (1.f / 1024.f);
  float var = ss * (1.f / 1024.f) - mu * mu;
  float rs = rsqrtf(var + 1e-6f);
  const float* shv = mod + b * 4096;
  const float* scv = mod + b * 4096 + 1024;
  float ph = 0.f;
  #pragma unroll
  for (int u = 0; u < 4; u++) {
    int d = t + u * 256;
    float y = (v[u] - mu) * rs * nsc[d] + nbi[d];
    float ym = y * (1.f + scv[d]) + shv[d];
    outp[(size_t)row * 1024 + d] = (bf16)ym;
    if (doobw) ph += ym * doobw[d];
  }
  if (doobw) {
    #pragma unroll
    for (int off = 1; off < 64; off <<= 1) ph += __shfl_xor(ph, off, 64);
    if ((t & 63) == 0) pb[t >> 6] = ph;
    __syncthreads();
    if (t == 0) phi[row] = pb[0] + pb[1] + pb[2] + pb[3];
  }
}

__global__ __launch_bounds__(256) void phimax_kernel(const float* __restrict__ phi,
                                                     float* __restrict__ pm) {
  int b = blockIdx.x;
  int t = threadIdx.x;
  float m = -1e30f;
  #pragma unroll
  for (int u = 0; u < 8; u++) m = fmaxf(m, phi[b * 2048 + t + u * 256]);
  #pragma unroll
  for (int off = 1; off < 64; off <<= 1) m = fmaxf(m, __shfl_xor(m, off, 64));
  __shared__ float mb[4];
  if ((t & 63) == 0) mb[t >> 6] = m;
  __syncthreads();
  if (t == 0) pm[b] = fmaxf(fmaxf(mb[0], mb[1]), fmaxf(mb[2], mb[3]));
}

// ============================================================
// bf16 MFMA GEMM w/ global_load_lds staging, XOR-swizzled LDS (stride 64, no pad)
// TM in {64,128}, N-tile = 128. 2x2 waves.
// MODE 10: token fused out: col<1024 -> qkh = val*sca, head-major (B,H,N,64);
//          col>=1024 -> vtb chunk-blocked (B,H,32nc,64dh,64c) with c=vperm(n&63)
//          [contiguous 8KB chunks; vperm makes flash's QK^T regs = PV A-frag]
// MODE 11: channel fused:   col<1024 -> qkct = val*scc (B,HC,128,N); col>=1024 -> v (B,N,D)
// MODE 4 : out = resid + val*gate (fp32, B,N,D)
// ============================================================
template <int MODE, int TM>
__global__ __launch_bounds__(256) void gemm_kernel(const bf16* __restrict__ A,
                                                   const bf16* __restrict__ Wt,
                                                   const float* __restrict__ scale,
                                                   const float* __restrict__ resid,
                                                   void* __restrict__ out0,
                                                   void* __restrict__ out1) {
  constexpr int K = 1024;
  constexpr int WM = TM / 2;       // wave rows
  constexpr int IT = WM / 16;      // i tiles per wave
  __shared__ bf16 As[TM * 64];
  __shared__ bf16 Bs[128 * 64];
  const int m0 = blockIdx.x * TM;
  const int n0 = blockIdx.y * 128;
  const int t = threadIdx.x, lane = t & 63, wid = t >> 6;
  const int wy = wid >> 1, wx = wid & 1;
  const int ml = lane & 15, quad = lane >> 4, rq = quad * 4, kq = quad * 8;
  // staging: lane -> (row srow, swizzled source chunk)
  const int srow = lane >> 3;
  const int schunk = (lane & 7) ^ srow;
  const bf16* gA = A  + (size_t)(m0 + wid * (TM / 4) + srow) * K + schunk * 8;
  const bf16* gB = Wt + (size_t)(n0 + wid * 32 + srow) * K + schunk * 8;
  bf16* lA = As + (wid * (TM / 4)) * 64;
  bf16* lB = Bs + (wid * 32) * 64;
  const int mlm = ml & 7;

  f32x4 acc[IT][4] = {};
  for (int k0 = 0; k0 < K; k0 += 64) {
    __syncthreads();
    #pragma unroll
    for (int q = 0; q < TM / 32; q++)
      gl16(gA + (size_t)q * 8 * K + k0, lA + q * 8 * 64);
    #pragma unroll
    for (int q = 0; q < 4; q++)
      gl16(gB + (size_t)q * 8 * K + k0, lB + q * 8 * 64);
    __syncthreads();
    #pragma unroll
    for (int ks = 0; ks < 2; ks++) {
      const int slot = ((ks * 4 + quad) ^ mlm) * 8;
      bf16x8 af[IT], bfv[4];
      #pragma unroll
      for (int i = 0; i < IT; i++)
        af[i] = *(const bf16x8*)(As + (wy * WM + i * 16 + ml) * 64 + slot);
      #pragma unroll
      for (int j = 0; j < 4; j++)
        bfv[j] = *(const bf16x8*)(Bs + (wx * 64 + j * 16 + ml) * 64 + slot);
      #pragma unroll
      for (int i = 0; i < IT; i++)
        #pragma unroll
        for (int j = 0; j < 4; j++)
          acc[i][j] = __builtin_amdgcn_mfma_f32_16x16x32_bf16(af[i], bfv[j], acc[i][j], 0, 0, 0);
    }
  }
  // epilogue
  #pragma unroll
  for (int i = 0; i < IT; i++) {
    #pragma unroll
    for (int j = 0; j < 4; j++) {
      int col = n0 + wx * 64 + j * 16 + ml;
      int row0 = m0 + wy * WM + i * 16 + rq;     // rows row0..row0+3, same b (row0 % 4 == 0)
      int b0 = row0 >> 11, nn0 = row0 & 2047;
      if constexpr (MODE == 10) {
        if (col < 1024) {
          int h = col >> 6, dh = col & 63;
          float sv = scale[b0 * 1024 + col];
          #pragma unroll
          for (int r = 0; r < 4; r++)
            ((bf16*)out0)[((size_t)(b0 * 16 + h) * 2048 + nn0 + r) * 64 + dh] =
                (bf16)(acc[i][j][r] * sv);
        } else {
          int c2 = col - 1024;
          int h = c2 >> 6, dh = c2 & 63;
          int c = vperm(nn0 & 63);               // low 2 bits preserved; nn0%4==0
          union { bf16x4 v; bf16x2 h2[2]; } pk;
          pk.h2[0] = cvt_pk_bf16(acc[i][j][0], acc[i][j][1]);
          pk.h2[1] = cvt_pk_bf16(acc[i][j][2], acc[i][j][3]);
          *(bf16x4*)((bf16*)out1 +
              (((size_t)(b0 * 16 + h) * 32 + (nn0 >> 6)) * 64 + dh) * 64 + c) = pk.v;
        }
      } else if constexpr (MODE == 11) {
        if (col < 1024) {
          float sv = scale[b0 * 1024 + col];
          union { bf16x4 v; bf16x2 h2[2]; } pk;
          pk.h2[0] = cvt_pk_bf16(acc[i][j][0] * sv, acc[i][j][1] * sv);
          pk.h2[1] = cvt_pk_bf16(acc[i][j][2] * sv, acc[i][j][3] * sv);
          *(bf16x4*)((bf16*)out0 +
              ((size_t)((b0 * 8 + (col >> 7)) * 128 + (col & 127))) * 2048 + nn0) = pk.v;
        } else {
          #pragma unroll
          for (int r = 0; r < 4; r++)
            ((bf16*)out1)[(size_t)(row0 + r) * 1024 + (col - 1024)] = (bf16)acc[i][j][r];
        }
      } else {
        float g = scale[b0 * 1024 + col];
        #pragma unroll
        for (int r = 0; r < 4; r++)
          ((float*)out0)[(size_t)(row0 + r) * 1024 + col] =
              resid[(size_t)(row0 + r) * 1024 + col] + acc[i][j][r] * g;
      }
    }
  }
}

// ============================================================
// q2 per (b,h,n) + e = (phi - q2 - phimax[b]) -- both pre-scaled by log2(e)
// head-major qkh input: one thread per (bh,n) row, 64 contiguous bf16.
// ============================================================
__global__ __launch_bounds__(256) void q2e_kernel(const bf16* __restrict__ qkh,
                                                  const float* __restrict__ phi,
                                                  const float* __restrict__ pm,
                                                  float* __restrict__ q2buf,
                                                  float* __restrict__ ebuf) {
  int idx = blockIdx.x * 256 + threadIdx.x;   // 0..65535 = bh*2048 + n
  int bh = idx >> 11, n = idx & 2047;
  int b = bh >> 4;
  const bf16* qr = qkh + (size_t)idx * 64;
  float q = 0.f;
  #pragma unroll
  for (int u = 0; u < 8; u++) {
    bf16x8 v = *(const bf16x8*)(qr + u * 8);
    #pragma unroll
    for (int e = 0; e < 8; e++) { float f = (float)v[e]; q += f * f; }
  }
  q2buf[idx] = q * 1.44269504f;
  ebuf[idx]  = (phi[b * 2048 + n] - q - pm[b]) * 1.44269504f;
}

// ============================================================
// Flash attention, static-max softmax, swapped-operand QK^T, register-P.
// Linear grid 1024, XCD-swizzled: bh = (bid&7)*4 + ((bid>>3)>>5), mt=(bid>>3)&31
// -> each bh's 512KB K/V L2-resident on one XCD (FETCH verified 8.5MB, r3).
// S^T = mfma(K,Q): lane holds P[q=ml][kv=16j+4quad+r]. vtb's columns are
// bit-permuted (vperm, written by gemm<10>) so these registers ARE the PV
// A-fragment: pa[ks] = pack(sacc[ks], sacc[2+ks]) -- no P LDS round-trip.
// e-biases double-buffered in LDS via size-4 global_load_lds (wave 0).
// K/V double-buffered via global_load_lds, source chunk XOR-involution.
// ============================================================
__global__ __launch_bounds__(256, 4) void flash_kernel(const bf16* __restrict__ qkh,  // (B,H,N,64)
                                                       const bf16* __restrict__ vtb,  // (B,H,32,64,64) vperm'd
                                                       const float* __restrict__ q2buf,
                                                       const float* __restrict__ ebuf,
                                                       bf16* __restrict__ wout) {     // (B,N,D)
  int bid = blockIdx.x;
  int ii = bid >> 3;
  int bh = (bid & 7) * 4 + (ii >> 5);   // 4 bh per XCD
  int mt = ii & 31;
  int b = bh >> 4, h = bh & 15;
  int m0 = mt * 64;
  int t = threadIdx.x, lane = t & 63, w = t >> 6;     // 4 waves
  int ml = lane & 15, quad = lane >> 4;
  int mlm = ml & 7;

  __shared__ __align__(16) bf16 Ks[2][64 * 64];
  __shared__ __align__(16) bf16 Vs[2][64 * 64];
  __shared__ __align__(16) float Es[2][64];

  // staging: thread owns 2x16B K chunks + 2x16B V chunks per kv-tile (4 gl16).
  // LDS dest is linear (gl16: wave base + lane*16); source chunk pre-swizzled.
  int sr = lane >> 3, swz = (lane & 7) ^ sr;
  const bf16* gK = qkh + ((size_t)bh * 2048 + w * 16 + sr) * 64 + swz * 8;
  const bf16* gV = vtb + (size_t)bh * 131072 + (w * 16 + sr) * 64 + swz * 8;
  const float* ep = ebuf + (size_t)bh * 2048;                // pre-scaled log2e

  // Q fragments in registers (loop-invariant); B-operand row = q = w*16+ml
  const bf16* qrow = qkh + ((size_t)bh * 2048 + m0 + w * 16 + ml) * 64;
  bf16x8 qf0 = *(const bf16x8*)(qrow + quad * 8);
  bf16x8 qf1 = *(const bf16x8*)(qrow + 32 + quad * 8);

  float q2l = q2buf[(size_t)bh * 2048 + m0 + w * 16 + ml];   // pre-scaled log2e

  f32x4 oacc[4] = {};
  float rs = 0.f;

  // prologue stage chunk 0 -> buf 0
  gl16(gK,       &Ks[0][w * 1024]);
  gl16(gK + 512, &Ks[0][w * 1024 + 512]);
  gl16(gV,       &Vs[0][w * 1024]);
  gl16(gV + 512, &Vs[0][w * 1024 + 512]);
  if (w == 0) gl4(ep + lane, Es[0]);

  #pragma unroll 2
  for (int nc = 0; nc < 32; nc++) {
    int cur = nc & 1;
    __syncthreads();                     // drains cur's stage (vmcnt 0) + barrier
    if (nc + 1 < 32) {                   // next chunk flies across this compute
      const bf16* nk = gK + (size_t)(nc + 1) * 4096;
      const bf16* nv = gV + (size_t)(nc + 1) * 4096;
      bf16* dk = &Ks[cur ^ 1][w * 1024];
      bf16* dv = &Vs[cur ^ 1][w * 1024];
      gl16(nk,       dk);
      gl16(nk + 512, dk + 512);
      gl16(nv,       dv);
      gl16(nv + 512, dv + 512);
      if (w == 0) gl4(ep + (nc + 1) * 64 + lane, Es[cur ^ 1]);
    }
    const bf16* Kc = Ks[cur];
    const bf16* Vc = Vs[cur];

    // S^T = K.Q^T : sacc[j][r] = S[kv=16j+4quad+r][q=ml]
    f32x4 sacc[4] = {};
    __builtin_amdgcn_s_setprio(1);
    #pragma unroll
    for (int ks = 0; ks < 2; ks++) {
      bf16x8 qb = ks ? qf1 : qf0;
      #pragma unroll
      for (int j = 0; j < 4; j++) {
        bf16x8 ka = *(const bf16x8*)(Kc + (j * 16 + ml) * 64 + ((4 * ks + quad) ^ mlm) * 8);
        sacc[j] = __builtin_amdgcn_mfma_f32_16x16x32_bf16(ka, qb, sacc[j], 0, 0, 0);
      }
    }
    __builtin_amdgcn_s_setprio(0);

    // softmax in registers: P[q=ml][kv=16j+4quad+r] = exp2(2.885*S + e - q2)
    float pv[4][4];
    #pragma unroll
    for (int j = 0; j < 4; j++) {
      float4 ev = *(const float4*)(&Es[cur][j * 16 + quad * 4]);
      pv[j][0] = exp2f(fmaf(2.88539008f, sacc[j][0], ev.x - q2l));
      pv[j][1] = exp2f(fmaf(2.88539008f, sacc[j][1], ev.y - q2l));
      pv[j][2] = exp2f(fmaf(2.88539008f, sacc[j][2], ev.z - q2l));
      pv[j][3] = exp2f(fmaf(2.88539008f, sacc[j][3], ev.w - q2l));
      rs += (pv[j][0] + pv[j][1]) + (pv[j][2] + pv[j][3]);
    }
    // pa[ks] = PV A-fragment directly (vperm'd V columns): no LDS round-trip
    union { bf16x8 v; bf16x2 h2[4]; } pa0, pa1;
    pa0.h2[0] = cvt_pk_bf16(pv[0][0], pv[0][1]);
    pa0.h2[1] = cvt_pk_bf16(pv[0][2], pv[0][3]);
    pa0.h2[2] = cvt_pk_bf16(pv[2][0], pv[2][1]);
    pa0.h2[3] = cvt_pk_bf16(pv[2][2], pv[2][3]);
    pa1.h2[0] = cvt_pk_bf16(pv[1][0], pv[1][1]);
    pa1.h2[1] = cvt_pk_bf16(pv[1][2], pv[1][3]);
    pa1.h2[2] = cvt_pk_bf16(pv[3][0], pv[3][1]);
    pa1.h2[3] = cvt_pk_bf16(pv[3][2], pv[3][3]);

    __builtin_amdgcn_s_setprio(1);
    #pragma unroll
    for (int ks = 0; ks < 2; ks++) {
      bf16x8 pa = ks ? pa1.v : pa0.v;
      #pragma unroll
      for (int jd = 0; jd < 4; jd++) {
        bf16x8 vb = *(const bf16x8*)(Vc + (jd * 16 + ml) * 64 + ((4 * ks + quad) ^ mlm) * 8);
        oacc[jd] = __builtin_amdgcn_mfma_f32_16x16x32_bf16(pa, vb, oacc[jd], 0, 0, 0);
      }
    }
    __builtin_amdgcn_s_setprio(0);
  }

  // row-sum: lane has partial for q = w*16+ml over its kv subset; fold quads
  rs += __shfl_xor(rs, 16, 64);
  rs += __shfl_xor(rs, 32, 64);
  float rinv = 1.f / rs;

  int rq = quad * 4;
  float rv[4];
  #pragma unroll
  for (int r = 0; r < 4; r++) rv[r] = __shfl(rinv, rq + r, 64);

  bf16* wrow = wout + (size_t)(b * 2048 + m0 + w * 16) * 1024 + h * 64;
  #pragma unroll
  for (int jd = 0; jd < 4; jd++)
    #pragma unroll
    for (int r = 0; r < 4; r++)
      wrow[(size_t)(rq + r) * 1024 + jd * 16 + ml] = (bf16)(oacc[jd][r] * rv[r]);
}

// ============================================================
// Channel attention
// ============================================================
// split-K Gram: grid (16 bh, 8 kslice): dotp[(ks*16+bh)][c][d] over 256-deep slice
__global__ __launch_bounds__(256) void gram_kernel(const bf16* __restrict__ qkct,
                                                   float* __restrict__ dotp) {
  int bh = blockIdx.x, ksl = blockIdx.y;
  const bf16* Q = qkct + (size_t)bh * 128 * 2048 + ksl * 256;
  __shared__ bf16 Ts[128 * 40];
  int t = threadIdx.x, lane = t & 63, w = t >> 6;
  int ml = lane & 15, kq = (lane >> 4) * 8, rq = (lane >> 4) * 4;
  f32x4 acc[2][8] = {};
  for (int k0 = 0; k0 < 256; k0 += 32) {
    __syncthreads();
    #pragma unroll
    for (int u = 0; u < 2; u++) {
      int idx = u * 256 + t;                 // 512 units: 128 rows x 4 x 16B
      int r = idx >> 2, seg = (idx & 3) * 8;
      *(uint4*)(Ts + r * 40 + seg) = *(const uint4*)(Q + (size_t)r * 2048 + k0 + seg);
    }
    __syncthreads();
    bf16x8 afr[2], bfr[8];
    #pragma unroll
    for (int i = 0; i < 2; i++) afr[i] = *(const bf16x8*)(Ts + (w * 32 + i * 16 + ml) * 40 + kq);
    #pragma unroll
    for (int j = 0; j < 8; j++) bfr[j] = *(const bf16x8*)(Ts + (j * 16 + ml) * 40 + kq);
    #pragma unroll
    for (int i = 0; i < 2; i++)
      #pragma unroll
      for (int j = 0; j < 8; j++)
        acc[i][j] = __builtin_amdgcn_mfma_f32_16x16x32_bf16(afr[i], bfr[j], acc[i][j], 0, 0, 0);
  }
  float* outp = dotp + ((size_t)ksl * 16 + bh) * 16384;
  #pragma unroll
  for (int i = 0; i < 2; i++)
    #pragma unroll
    for (int j = 0; j < 8; j++)
      #pragma unroll
      for (int r = 0; r < 4; r++) {
        int c = w * 32 + i * 16 + rq + r, d = j * 16 + ml;
        outp[c * 128 + d] = acc[i][j][r];
      }
}

// softmax over d, folding the 8-way partial sum. grid 2048 (bh*128+c), 128 thr.
__global__ __launch_bounds__(128) void chsm_kernel(const float* __restrict__ dotp,
                                                   const float* __restrict__ tau,
                                                   bf16* __restrict__ attnc) {
  int blk = blockIdx.x;
  int bh = blk >> 7, c = blk & 127, hc = bh & 7;
  int d = threadIdx.x;
  float dot = 0.f, dd = 0.f;
  #pragma unroll
  for (int kc = 0; kc < 8; kc++) {
    const float* pp = dotp + ((size_t)kc * 16 + bh) * 16384;
    dot += pp[c * 128 + d];
    dd  += pp[d * 128 + d];
  }
  __shared__ float diag[128];
  __shared__ float red[2], red2[2];
  diag[d] = dd;
  __syncthreads();
  float qc = diag[c];
  float sc = tau[hc] * rsqrtf(2048.f);
  float lg = sc * (2.f * dot - qc - dd);
  float mx = lg;
  #pragma unroll
  for (int off = 1; off < 64; off <<= 1) mx = fmaxf(mx, __shfl_xor(mx, off, 64));
  if ((d & 63) == 0) red[d >> 6] = mx;
  __syncthreads();
  mx = fmaxf(red[0], red[1]);
  float e = exp2f((lg - mx) * 1.44269504f);
  float sm = e;
  #pragma unroll
  for (int off = 1; off < 64; off <<= 1) sm += __shfl_xor(sm, off, 64);
  if ((d & 63) == 0) red2[d >> 6] = sm;
  __syncthreads();
  sm = red2[0] + red2[1];
  attnc[(size_t)bh * 16384 + c * 128 + d] = (bf16)(e / sm);
}

// wc[c][n] = sum_d attnc[c][d] * vc[b][n][hc*128+d]; write wcn (B,N,D)
__global__ __launch_bounds__(256) void chav_kernel(const bf16* __restrict__ attnc,
                                                   const bf16* __restrict__ vc,
                                                   bf16* __restrict__ wcn) {
  int nb = blockIdx.x, bh = blockIdx.y;
  int b = bh >> 3, hc = bh & 7;
  int n0 = nb * 64;
  __shared__ bf16 As[128 * 136];
  __shared__ bf16 Bs[64 * 136];
  int t = threadIdx.x, lane = t & 63, w = t >> 6;
  int ml = lane & 15, kq = (lane >> 4) * 8, rq = (lane >> 4) * 4;
  #pragma unroll
  for (int u = 0; u < 8; u++) {                  // A: 128 rows x 16 x 16B
    int idx = u * 256 + t;
    int r = idx >> 4, seg = (idx & 15) * 8;
    *(uint4*)(As + r * 136 + seg) = *(const uint4*)(attnc + (size_t)bh * 16384 + r * 128 + seg);
  }
  #pragma unroll
  for (int u = 0; u < 4; u++) {                  // B: 64 rows x 16 x 16B
    int idx = u * 256 + t;
    int r = idx >> 4, seg = (idx & 15) * 8;
    *(uint4*)(Bs + r * 136 + seg) =
        *(const uint4*)(vc + (size_t)(b * 2048 + n0 + r) * 1024 + hc * 128 + seg);
  }
  __syncthreads();
  f32x4 acc[2][4] = {};
  #pragma unroll
  for (int ks = 0; ks < 4; ks++) {
    bf16x8 afr[2], bfr[4];
    #pragma unroll
    for (int i = 0; i < 2; i++)
      afr[i] = *(const bf16x8*)(As + (w * 32 + i * 16 + ml) * 136 + ks * 32 + kq);
    #pragma unroll
    for (int j = 0; j < 4; j++)
      bfr[j] = *(const bf16x8*)(Bs + (j * 16 + ml) * 136 + ks * 32 + kq);
    #pragma unroll
    for (int i = 0; i < 2; i++)
      #pragma unroll
      for (int j = 0; j < 4; j++)
        acc[i][j] = __builtin_amdgcn_mfma_f32_16x16x32_bf16(afr[i], bfr[j], acc[i][j], 0, 0, 0);
  }
  #pragma unroll
  for (int i = 0; i < 2; i++)
    #pragma unroll
    for (int j = 0; j < 4; j++)
      #pragma unroll
      for (int r = 0; r < 4; r++) {
        int c = w * 32 + i * 16 + rq + r;
        int n = n0 + j * 16 + ml;
        wcn[(size_t)(b * 2048 + n) * 1024 + hc * 128 + c] = (bf16)acc[i][j][r];
      }
}

// ============================================================
// Host launcher
// ============================================================
extern "C" void kernel_launch(void* const* d_in, const int* in_sizes, int n_in,
                              void* d_out, int out_size, void* d_ws, size_t ws_size,
                              hipStream_t stream) {
  const float* x      = (const float*)d_in[0];
  const float* t      = (const float*)d_in[1];
  const float* n1s    = (const float*)d_in[2];
  const float* n1b    = (const float*)d_in[3];
  const float* n2s    = (const float*)d_in[4];
  const float* n2b    = (const float*)d_in[5];
  const float* tc_w1  = (const float*)d_in[6];
  const float* tc_b1  = (const float*)d_in[7];
  const float* tc_w2  = (const float*)d_in[8];
  const float* tc_b2  = (const float*)d_in[9];
  const float* tc_wa  = (const float*)d_in[10];
  const float* tc_ba  = (const float*)d_in[11];
  const float* tc_wc  = (const float*)d_in[12];
  const float* tc_bc  = (const float*)d_in[13];
  const float* aqk_w  = (const float*)d_in[14];
  const float* av_w   = (const float*)d_in[15];
  const float* aout_w = (const float*)d_in[16];
  const float* doobw  = (const float*)d_in[17];
  const float* cqk_w  = (const float*)d_in[19];
  const float* cv_w   = (const float*)d_in[20];
  const float* cout_w = (const float*)d_in[21];
  const float* tau    = (const float*)d_in[22];
  const float* g1     = (const float*)d_in[23];
  const float* g2     = (const float*)d_in[24];
  float* out = (float*)d_out;

  char* p = (char*)d_ws;
  auto alloc = [&](size_t bytes) -> void* {
    void* r = (void*)p;
    p += (bytes + 255) & ~(size_t)255;
    return r;
  };
  float* emb   = (float*)alloc(2 * 4096 * 4);
  float* partA = (float*)alloc(32 * 2 * 4096 * 4);
  float* partB = (float*)alloc(32 * 2 * 4096 * 4);
  float* h1    = (float*)alloc(2 * 4096 * 4);
  float* h2    = (float*)alloc(2 * 4096 * 4);
  float* avec  = (float*)alloc(2 * 4096 * 4);
  float* cvec  = (float*)alloc(2 * 4096 * 4);
  float* sca   = (float*)alloc(2 * 1024 * 4);
  float* scc   = (float*)alloc(2 * 1024 * 4);
  float* agv   = (float*)alloc(2 * 1024 * 4);
  float* cgv   = (float*)alloc(2 * 1024 * 4);
  float* phi   = (float*)alloc(4096 * 4);
  float* pmax  = (float*)alloc(2 * 4);
  float* q2buf = (float*)alloc(2 * 16 * 2048 * 4);
  float* ebuf  = (float*)alloc(2 * 16 * 2048 * 4);
  float* dotp  = (float*)alloc((size_t)8 * 16 * 16384 * 4);
  bf16* attnc  = (bf16*)alloc(16 * 128 * 128 * 2);
  bf16* wt     = (bf16*)alloc((size_t)6 * 1024 * 1024 * 2);
  bf16* xbf    = (bf16*)alloc((size_t)M_ * 1024 * 2);
  bf16* qkbf   = (bf16*)alloc((size_t)M_ * 1024 * 2);
  bf16* vbuf   = (bf16*)alloc((size_t)M_ * 1024 * 2);
  bf16* wbuf   = (bf16*)alloc((size_t)M_ * 1024 * 2);
  (void)ws_size; (void)in_sizes; (void)n_in; (void)out_size;

  // concatenated (N x K) weights: token [qk; v] (2048x1024), channel [cqk; cv]
  bf16* wt_tok  = wt;                              // 2048 x 1024
  bf16* wt_out  = wt + (size_t)2 * 1048576;        // 1024 x 1024
  bf16* wt_ch   = wt + (size_t)3 * 1048576;        // 2048 x 1024
  bf16* wt_cout = wt + (size_t)5 * 1048576;        // 1024 x 1024

  dim3 blk(256);
  wtconv6_kernel<<<dim3(32, 32, 6), blk, 0, stream>>>(
      aqk_w, av_w, aout_w, cqk_w, cv_w, cout_w,
      wt_tok, wt_tok + (size_t)1048576, wt_out,
      wt_ch,  wt_ch  + (size_t)1048576, wt_cout);

  // --- stage A: time conditioning ---
  emb_kernel<<<32, blk, 0, stream>>>(t, emb);
  gemv_kernel<<<dim3(8, 32), blk, 0, stream>>>(emb, tc_w1, partA);
  gemv_reduce_kernel<<<32, blk, 0, stream>>>(partA, tc_b1, h1, 1);
  gemv_kernel<<<dim3(8, 32), blk, 0, stream>>>(h1, tc_w2, partA);
  gemv_reduce_kernel<<<32, blk, 0, stream>>>(partA, tc_b2, h2, 1);
  gemv_kernel<<<dim3(8, 32), blk, 0, stream>>>(h2, tc_wa, partA);
  gemv_kernel<<<dim3(8, 32), blk, 0, stream>>>(h2, tc_wc, partB);
  gemv_reduce_kernel<<<32, blk, 0, stream>>>(partA, tc_ba, avec, 0);
  gemv_reduce_kernel<<<32, blk, 0, stream>>>(partB, tc_bc, cvec, 0);
  postA_kernel<<<8, blk, 0, stream>>>(avec, cvec, g1, g2, sca, scc, agv, cgv);

  // --- token attention ---
  ln_mod_kernel<<<4096, blk, 0, stream>>>(x, n1s, n1b, avec, doobw, phi, xbf);
  phimax_kernel<<<2, blk, 0, stream>>>(phi, pmax);
  gemm_kernel<10, 128><<<dim3(32, 16), blk, 0, stream>>>(xbf, wt_tok, sca, nullptr, qkbf, vbuf);
  q2e_kernel<<<256, blk, 0, stream>>>(qkbf, phi, pmax, q2buf, ebuf);
  flash_kernel<<<dim3(1024), dim3(256), 0, stream>>>(qkbf, vbuf, q2buf, ebuf, wbuf);
  gemm_kernel<4, 64><<<dim3(64, 8), blk, 0, stream>>>(wbuf, wt_out, agv, x, out, nullptr);

  // --- channel attention ---
  ln_mod_kernel<<<4096, blk, 0, stream>>>(out, n2s, n2b, cvec, nullptr, nullptr, xbf);
  gemm_kernel<11, 128><<<dim3(32, 16), blk, 0, stream>>>(xbf, wt_ch, scc, nullptr, qkbf, vbuf);
  gram_kernel<<<dim3(16, 8), blk, 0, stream>>>(qkbf, dotp);
  chsm_kernel<<<2048, dim3(128), 0, stream>>>(dotp, tau, attnc);
  chav_kernel<<<dim3(32, 16), blk, 0, stream>>>(attnc, vbuf, wbuf);
  gemm_kernel<4, 64><<<dim3(64, 8), blk, 0, stream>>>(wbuf, wt_cout, cgv, out, out, nullptr);
}